// Round 16
// baseline (1882.524 us; speedup 1.0000x reference)
//
#include <hip/hip_runtime.h>
#include <hip/hip_bf16.h>

typedef unsigned short u16;
typedef unsigned int u32;
typedef __attribute__((ext_vector_type(8))) short short8v;
typedef __attribute__((ext_vector_type(4))) float f32x4;

// Problem dims
#define BB    4
#define NN    2048
#define DDIM  1024
#define HH    16
#define DH    64
#define MM    256
#define FDIM  4096
#define LL    4
#define QLD   3072   // fused qkv row stride

static constexpr float DN_    = 0.35355339059327373f;  // 64^-0.25
static constexpr float RATIO_ = 0.0625f;               // 256^-0.5
static constexpr float KEPS_  = 1e-4f;

__device__ __forceinline__ short f2bs(float f) {
  __hip_bfloat16 h = __float2bfloat16(f);
  return *(short*)&h;
}
__device__ __forceinline__ float bs2f(short s) {
  return __uint_as_float(((unsigned)(u16)s) << 16);
}
// A&S 7.1.26 erf, abs err <= 1.5e-7 (<< bf16 ulp)
__device__ __forceinline__ float erf_fast(float x) {
  float ax = fabsf(x);
  float t = 1.f / (1.f + 0.3275911f * ax);
  float y = t * (0.254829592f + t * (-0.284496736f + t * (1.421413741f +
            t * (-1.453152027f + t * 1.061405429f))));
  float r = 1.f - y * __expf(-ax * ax);
  return copysignf(r, x);
}

// async global->LDS 16B: LDS dest wave-uniform base + lane*16
__device__ __forceinline__ void gload_lds16(const void* g, void* l) {
  __builtin_amdgcn_global_load_lds(
      (const __attribute__((address_space(1))) u32*)g,
      (__attribute__((address_space(3))) u32*)l, 16, 0, 0);
}

// ---------------------------------------------------------------- diagnostics
__global__ __launch_bounds__(256) void k_sentinel(float* __restrict__ out, float val) {
  int i = blockIdx.x * 256 + threadIdx.x;
  if (i < BB * DDIM) out[i] = val;
}

// ---------------------------------------------------------------- embed + LN1(layer0) fused
__global__ __launch_bounds__(256) void k_embed_ln(const int* __restrict__ x,
    const float* __restrict__ tok, const float* __restrict__ pos,
    const float* __restrict__ g, const float* __restrict__ b,
    float* __restrict__ h, __hip_bfloat16* __restrict__ zb) {
  int r = blockIdx.x, t = threadIdx.x;
  int n = r & (NN - 1);
  int id = x[r];
  const float* tr = tok + (size_t)id * DDIM;
  const float* pr = pos + (size_t)n * DDIM;
  float* hr = h + (size_t)r * DDIM;
  float v[4], s = 0.f, s2 = 0.f;
#pragma unroll
  for (int i = 0; i < 4; i++) {
    int d = t + i * 256;
    v[i] = tr[d] + pr[d];
    hr[d] = v[i];
    s += v[i]; s2 += v[i] * v[i];
  }
#pragma unroll
  for (int o = 32; o > 0; o >>= 1) { s += __shfl_down(s, o); s2 += __shfl_down(s2, o); }
  __shared__ float ws[8];
  int wid = t >> 6, lane = t & 63;
  if (lane == 0) { ws[wid] = s; ws[4 + wid] = s2; }
  __syncthreads();
  s = ws[0] + ws[1] + ws[2] + ws[3];
  s2 = ws[4] + ws[5] + ws[6] + ws[7];
  float mu = s * (1.f / DDIM);
  float var = s2 * (1.f / DDIM) - mu * mu;
  float rstd = rsqrtf(var + 1e-5f);
  __hip_bfloat16* orow = zb + (size_t)r * DDIM;
#pragma unroll
  for (int i = 0; i < 4; i++) {
    int d = t + i * 256;
    orow[d] = __float2bfloat16((v[i] - mu) * rstd * g[d] + b[d]);
  }
}

// ---------------------------------------------------------------- layernorm (bf16 out)
__global__ __launch_bounds__(256) void k_ln(const float* __restrict__ in,
    const float* __restrict__ g, const float* __restrict__ b,
    __hip_bfloat16* __restrict__ out) {
  int r = blockIdx.x, t = threadIdx.x;
  const float* xr = in + (size_t)r * DDIM;
  float v[4], s = 0.f, s2 = 0.f;
#pragma unroll
  for (int i = 0; i < 4; i++) {
    v[i] = xr[t + i * 256];
    s += v[i]; s2 += v[i] * v[i];
  }
#pragma unroll
  for (int o = 32; o > 0; o >>= 1) { s += __shfl_down(s, o); s2 += __shfl_down(s2, o); }
  __shared__ float ws[8];
  int wid = t >> 6, lane = t & 63;
  if (lane == 0) { ws[wid] = s; ws[4 + wid] = s2; }
  __syncthreads();
  s = ws[0] + ws[1] + ws[2] + ws[3];
  s2 = ws[4] + ws[5] + ws[6] + ws[7];
  float mu = s * (1.f / DDIM);
  float var = s2 * (1.f / DDIM) - mu * mu;
  float rstd = rsqrtf(var + 1e-5f);
  __hip_bfloat16* orow = out + (size_t)r * DDIM;
#pragma unroll
  for (int i = 0; i < 4; i++) {
    int d = t + i * 256;
    orow[d] = __float2bfloat16((v[i] - mu) * rstd * g[d] + b[d]);
  }
}

// ---------------------------------------------------------------- ALL weight transposes + bias concat, one dispatch
__global__ __launch_bounds__(256) void k_wtall(const float* __restrict__ Wq,
    const float* __restrict__ Wk, const float* __restrict__ Wv,
    const float* __restrict__ Wo, const float* __restrict__ W1,
    const float* __restrict__ W2, const float* __restrict__ bq,
    const float* __restrict__ bk, const float* __restrict__ bv,
    __hip_bfloat16* __restrict__ wt, float* __restrict__ bcat) {
  int id = blockIdx.x;
  int t = threadIdx.x;
  if (id >= 3072) {                     // bias concat: 12 blocks
    int i = (id - 3072) * 256 + t;
    bcat[i] = i < 1024 ? bq[i] : (i < 2048 ? bk[i - 1024] : bv[i - 2048]);
    return;
  }
  const float* W;
  __hip_bfloat16* Wt;
  int K, N, n0, k0;
  if (id < 1024) {                      // Wq|Wk|Wv|Wo: 256 tiles each
    int which = id >> 8, local = id & 255;
    W = which == 0 ? Wq : which == 1 ? Wk : which == 2 ? Wv : Wo;
    Wt = wt + (size_t)which * 1048576;
    K = 1024; N = 1024;
    n0 = (local & 15) * 64; k0 = (local >> 4) * 64;
  } else if (id < 2048) {               // W1: K=1024, N=4096
    int local = id - 1024;
    W = W1; Wt = wt + (size_t)4 * 1048576;
    K = 1024; N = 4096;
    n0 = (local & 63) * 64; k0 = (local >> 6) * 64;
  } else {                              // W2: K=4096, N=1024
    int local = id - 2048;
    W = W2; Wt = wt + (size_t)8 * 1048576;
    K = 4096; N = 1024;
    n0 = (local & 15) * 64; k0 = (local >> 4) * 64;
  }
  __shared__ float tl[64][68];
#pragma unroll
  for (int i = 0; i < 4; i++) {
    int kl = (t >> 4) + i * 16;
    float4 f = *(const float4*)&W[(size_t)(k0 + kl) * N + n0 + (t & 15) * 4];
    tl[kl][(t & 15) * 4 + 0] = f.x;
    tl[kl][(t & 15) * 4 + 1] = f.y;
    tl[kl][(t & 15) * 4 + 2] = f.z;
    tl[kl][(t & 15) * 4 + 3] = f.w;
  }
  __syncthreads();
  int nl = t >> 2;
#pragma unroll
  for (int i = 0; i < 4; i++) {
    int kl = (t & 3) * 4 + i * 16;
    size_t ob = (size_t)(n0 + nl) * K + k0 + kl;
    Wt[ob + 0] = __float2bfloat16(tl[kl + 0][nl]);
    Wt[ob + 1] = __float2bfloat16(tl[kl + 1][nl]);
    Wt[ob + 2] = __float2bfloat16(tl[kl + 2][nl]);
    Wt[ob + 3] = __float2bfloat16(tl[kl + 3][nl]);
  }
}

// ---------------------------------------------------------------- MFMA GEMM 128x128 (r15, verified)
template <bool GELU, bool RES, bool OUTF32>
__global__ __launch_bounds__(256) void k_gemm_mfma(
    const u16* __restrict__ A, const u16* __restrict__ Bt,
    const float* __restrict__ bias, const float* __restrict__ Cin,
    void* __restrict__ Cout, int M, int K, int Nc) {
  __shared__ short As[2][128 * 32];
  __shared__ short Bs[2][128 * 32];
  int t = threadIdx.x;
  int lane = t & 63, w = t >> 6;
  int wr = w >> 1, wc = w & 1;
  int nwg = gridDim.x * gridDim.y;
  int id = blockIdx.y * gridDim.x + blockIdx.x;
  int swz = (id & 7) * (nwg >> 3) + (id >> 3);
  int bx = swz % gridDim.x, by = swz / gridDim.x;
  int row0 = by * 128, col0 = bx * 128;
  f32x4 acc[4][4];
  f32x4 z4 = {0.f, 0.f, 0.f, 0.f};
#pragma unroll
  for (int i = 0; i < 4; i++)
#pragma unroll
    for (int j = 0; j < 4; j++) acc[i][j] = z4;
  int fr = lane & 15;
  int fc = lane >> 4;
  int offA[4], offB[4];
#pragma unroll
  for (int f = 0; f < 4; f++) {
    int ra = wr * 64 + f * 16 + fr;
    offA[f] = ra * 32 + (fc ^ ((ra >> 1) & 3)) * 8;
    int rb = wc * 64 + f * 16 + fr;
    offB[f] = rb * 32 + (fc ^ ((rb >> 1) & 3)) * 8;
  }
  int c0 = t, c1 = 256 + t;
  int r0 = c0 >> 2, cl0 = (c0 & 3) ^ ((r0 >> 1) & 3);
  int r1 = c1 >> 2, cl1 = (c1 & 3) ^ ((r1 >> 1) & 3);
  const u16* pA0 = A + (size_t)(row0 + r0) * K + cl0 * 8;
  const u16* pA1 = A + (size_t)(row0 + r1) * K + cl1 * 8;
  const u16* pB0 = Bt + (size_t)(col0 + r0) * K + cl0 * 8;
  const u16* pB1 = Bt + (size_t)(col0 + r1) * K + cl1 * 8;

  auto STG = [&](short* Ab, short* Bb) {
    gload_lds16(pA0, Ab + c0 * 8);
    gload_lds16(pA1, Ab + c1 * 8);
    gload_lds16(pB0, Bb + c0 * 8);
    gload_lds16(pB1, Bb + c1 * 8);
    pA0 += 32; pA1 += 32; pB0 += 32; pB1 += 32;
  };
  auto COMPUTE = [&](const short* Ab, const short* Bb) {
    short8v af[4], bfr[4];
#pragma unroll
    for (int f = 0; f < 4; f++) {
      af[f] = *(const short8v*)(Ab + offA[f]);
      bfr[f] = *(const short8v*)(Bb + offB[f]);
    }
#pragma unroll
    for (int fi = 0; fi < 4; fi++)
#pragma unroll
      for (int fj = 0; fj < 4; fj++)
        acc[fi][fj] = __builtin_amdgcn_mfma_f32_16x16x32_bf16(
            af[fi], bfr[fj], acc[fi][fj], 0, 0, 0);
  };

  int KT = K >> 5;            // even at all call sites
  STG(As[0], Bs[0]);
  __syncthreads();
  for (int kt = 0; kt < KT - 2; kt += 2) {
    STG(As[1], Bs[1]);
    COMPUTE(As[0], Bs[0]);
    __syncthreads();
    STG(As[0], Bs[0]);
    COMPUTE(As[1], Bs[1]);
    __syncthreads();
  }
  STG(As[1], Bs[1]);
  COMPUTE(As[0], Bs[0]);
  __syncthreads();
  COMPUTE(As[1], Bs[1]);
#pragma unroll
  for (int fi = 0; fi < 4; fi++) {
#pragma unroll
    for (int fj = 0; fj < 4; fj++) {
#pragma unroll
      for (int ri = 0; ri < 4; ri++) {
        int row = row0 + wr * 64 + fi * 16 + (lane >> 4) * 4 + ri;
        int col = col0 + wc * 64 + fj * 16 + fr;
        float vv = acc[fi][fj][ri] + bias[col];
        if (GELU) vv = 0.5f * vv * (1.f + erf_fast(vv * 0.70710678118f));
        if (RES) vv += Cin[(size_t)row * Nc + col];
        if (OUTF32) ((float*)Cout)[(size_t)row * Nc + col] = vv;
        else ((__hip_bfloat16*)Cout)[(size_t)row * Nc + col] = __float2bfloat16(vv);
      }
    }
  }
}

// ---------------------------------------------------------------- MFMA GEMM 256x256 (512 thr, 8 waves 2x4)
// Same 2-phase sync + swizzles as 128^2; 32 MFMA/barrier/wave, 2 blocks/CU.
template <bool GELU, bool OUTF32>
__global__ __launch_bounds__(512) void k_gemm_mfma256(
    const u16* __restrict__ A, const u16* __restrict__ Bt,
    const float* __restrict__ bias, void* __restrict__ Cout,
    int M, int K, int Nc) {
  __shared__ short As[2][256 * 32];
  __shared__ short Bs[2][256 * 32];
  int t = threadIdx.x;
  int lane = t & 63, wid = t >> 6;
  int wr = wid >> 2, wc = wid & 3;
  int nwg = gridDim.x * gridDim.y;
  int id = blockIdx.y * gridDim.x + blockIdx.x;
  int swz = (id & 7) * (nwg >> 3) + (id >> 3);
  int bx = swz % gridDim.x, by = swz / gridDim.x;
  int row0 = by * 256, col0 = bx * 256;
  f32x4 acc[8][4];
  f32x4 z4 = {0.f, 0.f, 0.f, 0.f};
#pragma unroll
  for (int i = 0; i < 8; i++)
#pragma unroll
    for (int j = 0; j < 4; j++) acc[i][j] = z4;
  int fr = lane & 15;
  int fc = lane >> 4;
  int offA[8], offB[4];
#pragma unroll
  for (int f = 0; f < 8; f++) {
    int ra = wr * 128 + f * 16 + fr;
    offA[f] = ra * 32 + (fc ^ ((ra >> 1) & 3)) * 8;
  }
#pragma unroll
  for (int f = 0; f < 4; f++) {
    int rb = wc * 64 + f * 16 + fr;
    offB[f] = rb * 32 + (fc ^ ((rb >> 1) & 3)) * 8;
  }
  int c0 = t, c1 = 512 + t;               // 1024 chunks per operand
  int r0 = c0 >> 2, cl0 = (c0 & 3) ^ ((r0 >> 1) & 3);
  int r1 = c1 >> 2, cl1 = (c1 & 3) ^ ((r1 >> 1) & 3);
  const u16* pA0 = A + (size_t)(row0 + r0) * K + cl0 * 8;
  const u16* pA1 = A + (size_t)(row0 + r1) * K + cl1 * 8;
  const u16* pB0 = Bt + (size_t)(col0 + r0) * K + cl0 * 8;
  const u16* pB1 = Bt + (size_t)(col0 + r1) * K + cl1 * 8;

  auto STG = [&](short* Ab, short* Bb) {
    gload_lds16(pA0, Ab + c0 * 8);
    gload_lds16(pA1, Ab + c1 * 8);
    gload_lds16(pB0, Bb + c0 * 8);
    gload_lds16(pB1, Bb + c1 * 8);
    pA0 += 32; pA1 += 32; pB0 += 32; pB1 += 32;
  };
  auto COMPUTE = [&](const short* Ab, const short* Bb) {
    short8v af[8], bfr[4];
#pragma unroll
    for (int f = 0; f < 8; f++) af[f] = *(const short8v*)(Ab + offA[f]);
#pragma unroll
    for (int f = 0; f < 4; f++) bfr[f] = *(const short8v*)(Bb + offB[f]);
#pragma unroll
    for (int fi = 0; fi < 8; fi++)
#pragma unroll
      for (int fj = 0; fj < 4; fj++)
        acc[fi][fj] = __builtin_amdgcn_mfma_f32_16x16x32_bf16(
            af[fi], bfr[fj], acc[fi][fj], 0, 0, 0);
  };

  int KT = K >> 5;            // even (32 at both call sites)
  STG(As[0], Bs[0]);
  __syncthreads();
  for (int kt = 0; kt < KT - 2; kt += 2) {
    STG(As[1], Bs[1]);
    COMPUTE(As[0], Bs[0]);
    __syncthreads();
    STG(As[0], Bs[0]);
    COMPUTE(As[1], Bs[1]);
    __syncthreads();
  }
  STG(As[1], Bs[1]);
  COMPUTE(As[0], Bs[0]);
  __syncthreads();
  COMPUTE(As[1], Bs[1]);
#pragma unroll
  for (int fi = 0; fi < 8; fi++) {
#pragma unroll
    for (int fj = 0; fj < 4; fj++) {
#pragma unroll
      for (int ri = 0; ri < 4; ri++) {
        int row = row0 + wr * 128 + fi * 16 + (lane >> 4) * 4 + ri;
        int col = col0 + wc * 64 + fj * 16 + fr;
        float vv = acc[fi][fj][ri] + bias[col];
        if (GELU) vv = 0.5f * vv * (1.f + erf_fast(vv * 0.70710678118f));
        if (OUTF32) ((float*)Cout)[(size_t)row * Nc + col] = vv;
        else ((__hip_bfloat16*)Cout)[(size_t)row * Nc + col] = __float2bfloat16(vv);
      }
    }
  }
}

// ---------------------------------------------------------------- fused key-side, MFMA, online-max, m-split
__global__ __launch_bounds__(256) void k_kv(const u16* __restrict__ kq,
    const u16* __restrict__ vq, const float* __restrict__ P,
    float* __restrict__ es, float* __restrict__ mxc, float* __restrict__ svc,
    float* __restrict__ ctx_part) {
  int bh = blockIdx.x >> 3;
  int chunk = (blockIdx.x >> 1) & 3;
  int mh = blockIdx.x & 1;
  int b = bh >> 4, hh = bh & 15;
  int t = threadIdx.x, lane = t & 63, w = t >> 6;
  int fr = lane & 15, kc = lane >> 4;
  __shared__ short Pl[128 * 64];
  __shared__ short ksl[32 * 64];
  __shared__ short vtl[64 * 32];
  __shared__ short kpl[128 * 32];
  __shared__ float dgs[32];
  __shared__ float wredk[4];
  __shared__ float svl[32][64];
#pragma unroll
  for (int i = 0; i < 4; i++) {
    int e = i * 256 + t;
    int m = e >> 3, j = e & 7;
    const float* src = P + (size_t)(mh * 128 + m) * 64 + j * 8;
    float4 f0 = *(const float4*)src;
    float4 f1 = *(const float4*)(src + 4);
    short* dst = Pl + m * 64 + ((j ^ (m & 7)) << 3);
    dst[0] = f2bs(f0.x); dst[1] = f2bs(f0.y); dst[2] = f2bs(f0.z); dst[3] = f2bs(f0.w);
    dst[4] = f2bs(f1.x); dst[5] = f2bs(f1.y); dst[6] = f2bs(f1.z); dst[7] = f2bs(f1.w);
  }
  f32x4 z4 = {0.f, 0.f, 0.f, 0.f};
  f32x4 accc[2][4];
#pragma unroll
  for (int i = 0; i < 2; i++)
#pragma unroll
    for (int j = 0; j < 4; j++) accc[i][j] = z4;
  float ksp[2] = {0.f, 0.f};
  float svp[8] = {0.f, 0.f, 0.f, 0.f, 0.f, 0.f, 0.f, 0.f};
  float m_run = -3e38f;
  int r8 = t >> 3, j8 = t & 7;
  for (int tile = 0; tile < 16; ++tile) {
    int n0 = chunk * 512 + tile * 32;
    __syncthreads();
    {
      size_t gk = ((size_t)(b * NN) + n0 + r8) * QLD + hh * 64 + j8 * 8;
      short8v k8 = *(const short8v*)(kq + gk);
      *(short8v*)(ksl + r8 * 64 + ((j8 ^ (r8 & 7)) << 3)) = k8;
      float s2 = 0.f;
#pragma unroll
      for (int ii = 0; ii < 8; ii++) { float rv = bs2f(k8[ii]); s2 += rv * rv; }
      s2 += __shfl_down(s2, 4); s2 += __shfl_down(s2, 2); s2 += __shfl_down(s2, 1);
      if (j8 == 0) dgs[r8] = 0.0625f * s2;
      short8v v8 = *(const short8v*)(vq + gk);
#pragma unroll
      for (int ii = 0; ii < 8; ii++) {
        int d = j8 * 8 + ii;
        vtl[d * 32 + (((r8 >> 3) ^ ((d >> 1) & 3)) << 3) + (r8 & 7)] = v8[ii];
        svp[ii] += bs2f(v8[ii]);
      }
    }
    __syncthreads();
    f32x4 accd[2][2];
#pragma unroll
    for (int nt = 0; nt < 2; nt++)
#pragma unroll
      for (int mt = 0; mt < 2; mt++) accd[nt][mt] = z4;
#pragma unroll
    for (int s = 0; s < 2; s++) {
      short8v afr[2];
#pragma unroll
      for (int nt = 0; nt < 2; nt++) {
        int rr = nt * 16 + fr;
        afr[nt] = *(const short8v*)(ksl + rr * 64 + (((s * 4 + kc) ^ (rr & 7)) << 3));
      }
#pragma unroll
      for (int mt = 0; mt < 2; mt++) {
        int ml = w * 32 + mt * 16 + fr;
        short8v bfp = *(const short8v*)(Pl + ml * 64 + (((s * 4 + kc) ^ (ml & 7)) << 3));
#pragma unroll
        for (int nt = 0; nt < 2; nt++)
          accd[nt][mt] = __builtin_amdgcn_mfma_f32_16x16x32_bf16(afr[nt], bfp, accd[nt][mt], 0, 0, 0);
      }
    }
    float tm = -3e38f;
#pragma unroll
    for (int nt = 0; nt < 2; nt++)
#pragma unroll
      for (int mt = 0; mt < 2; mt++) {
        accd[nt][mt] = accd[nt][mt] * DN_;
        tm = fmaxf(tm, fmaxf(fmaxf(accd[nt][mt][0], accd[nt][mt][1]),
                             fmaxf(accd[nt][mt][2], accd[nt][mt][3])));
      }
#pragma unroll
    for (int o = 32; o > 0; o >>= 1) tm = fmaxf(tm, __shfl_xor(tm, o));
    if (lane == 0) wredk[w] = tm;
    __syncthreads();
    float bm = fmaxf(fmaxf(wredk[0], wredk[1]), fmaxf(wredk[2], wredk[3]));
    float nm = fmaxf(m_run, bm);
    float fac = __expf(m_run - nm);
#pragma unroll
    for (int mt = 0; mt < 2; mt++) {
      ksp[mt] *= fac;
#pragma unroll
      for (int dt = 0; dt < 4; dt++) accc[mt][dt] = accc[mt][dt] * fac;
    }
    m_run = nm;
#pragma unroll
    for (int nt = 0; nt < 2; nt++)
#pragma unroll
      for (int mt = 0; mt < 2; mt++)
#pragma unroll
        for (int ri = 0; ri < 4; ri++) {
          int n = nt * 16 + kc * 4 + ri;
          int ml = w * 32 + mt * 16 + fr;
          float kpv = __expf(accd[nt][mt][ri] - dgs[n] - m_run);
          ksp[mt] += kpv;
          kpl[ml * 32 + (((n >> 3) ^ ((ml >> 1) & 3)) << 3) + (n & 7)] = f2bs(kpv);
        }
    short8v bvv[4];
#pragma unroll
    for (int dt = 0; dt < 4; dt++) {
      int d = dt * 16 + fr;
      bvv[dt] = *(const short8v*)(vtl + d * 32 + ((kc ^ ((d >> 1) & 3)) << 3));
    }
#pragma unroll
    for (int mt = 0; mt < 2; mt++) {
      int ml = w * 32 + mt * 16 + fr;
      short8v ak = *(const short8v*)(kpl + ml * 32 + ((kc ^ ((ml >> 1) & 3)) << 3));
#pragma unroll
      for (int dt = 0; dt < 4; dt++)
        accc[mt][dt] = __builtin_amdgcn_mfma_f32_16x16x32_bf16(ak, bvv[dt], accc[mt][dt], 0, 0, 0);
    }
  }
#pragma unroll
  for (int mt = 0; mt < 2; mt++) {
    float vv = ksp[mt];
    vv += __shfl_xor(vv, 16);
    vv += __shfl_xor(vv, 32);
    if (lane < 16)
      es[((size_t)bh * 4 + chunk) * MM + mh * 128 + w * 32 + mt * 16 + lane] = vv;
  }
  if (t == 0) mxc[((size_t)bh * 4 + chunk) * 2 + mh] = m_run;
#pragma unroll
  for (int ii = 0; ii < 8; ii++) svl[r8][j8 * 8 + ii] = svp[ii];
  __syncthreads();
  if (mh == 0 && t < 64) {
    float s = 0.f;
#pragma unroll
    for (int r = 0; r < 32; r++) s += svl[r][t];
    svc[((size_t)bh * 4 + chunk) * 64 + t] = s;
  }
  size_t base = ((size_t)(chunk * 64 + bh)) * MM * DH;
#pragma unroll
  for (int mt = 0; mt < 2; mt++)
#pragma unroll
    for (int dt = 0; dt < 4; dt++)
#pragma unroll
      for (int ri = 0; ri < 4; ri++) {
        int mg = mh * 128 + w * 32 + mt * 16 + kc * 4 + ri;
        int d = dt * 16 + fr;
        ctx_part[base + mg * 64 + d] = accc[mt][dt][ri];
      }
}

// ---------------------------------------------------------------- combine 4chunks x 2mhalves
__global__ __launch_bounds__(256) void k_ctxred(const float* __restrict__ part,
    const float* __restrict__ es, const float* __restrict__ mxc,
    const float* __restrict__ svc, float* __restrict__ ksum,
    u16* __restrict__ ctxT) {
  int bh = blockIdx.x, t = threadIdx.x;
  __shared__ float tl[64][65];
  __shared__ float facs[8];
  __shared__ float svg[64];
  float mg = -3e38f;
#pragma unroll
  for (int i = 0; i < 8; i++) mg = fmaxf(mg, mxc[(size_t)bh * 8 + i]);
  if (t < 8) facs[t] = __expf(mxc[(size_t)bh * 8 + t] - mg);
  if (t >= 64 && t < 128) {
    int d = t - 64;
    svg[d] = svc[((size_t)bh * 4 + 0) * 64 + d] + svc[((size_t)bh * 4 + 1) * 64 + d] +
             svc[((size_t)bh * 4 + 2) * 64 + d] + svc[((size_t)bh * 4 + 3) * 64 + d];
  }
  __syncthreads();
  {
    size_t eb = (size_t)bh * 4 * MM;
    int mhb = t >> 7;
    float s = es[eb + t] * facs[0 * 2 + mhb] + es[eb + MM + t] * facs[1 * 2 + mhb] +
              es[eb + 2 * MM + t] * facs[2 * 2 + mhb] + es[eb + 3 * MM + t] * facs[3 * 2 + mhb];
    ksum[bh * MM + t] = RATIO_ * (s + KEPS_ * 2048.0f);
  }
  const size_t CH = (size_t)64 * MM * DH;
  for (int mt = 0; mt < 4; mt++) {
    int mhb = mt >> 1;
    float f0 = facs[0 * 2 + mhb], f1 = facs[1 * 2 + mhb];
    float f2 = facs[2 * 2 + mhb], f3 = facs[3 * 2 + mhb];
    __syncthreads();
#pragma unroll
    for (int i = 0; i < 16; i++) {
      int e = i * 256 + t;
      int ml = e >> 6, d = e & 63;
      size_t off = (size_t)bh * MM * DH + (size_t)(mt * 64 + ml) * 64 + d;
      float ev = part[off] * f0 + part[CH + off] * f1 +
                 part[2 * CH + off] * f2 + part[3 * CH + off] * f3;
      tl[ml][d] = RATIO_ * (ev + KEPS_ * svg[d]);
    }
    __syncthreads();
#pragma unroll
    for (int i = 0; i < 16; i++) {
      int e = i * 256 + t;
      int d = e >> 6, ml = e & 63;
      ctxT[((size_t)bh * 64 + d) * 256 + mt * 64 + ml] = (u16)f2bs(tl[ml][d]);
    }
  }
}

// ---------------------------------------------------------------- fused query-side, MFMA (verified r12)
__global__ __launch_bounds__(256) void k_attn_fused(const u16* __restrict__ q,
    const float* __restrict__ P, const float* __restrict__ ksum,
    const u16* __restrict__ ctxT, __hip_bfloat16* __restrict__ attn) {
  int bh = blockIdx.x >> 5, rb = blockIdx.x & 31;
  int b = bh >> 4, hh = bh & 15;
  int n0 = rb * 64;
  int t = threadIdx.x, lane = t & 63, w = t >> 6;
  int fr = lane & 15, kc = lane >> 4;
  __shared__ short qsl[64 * 64];
  __shared__ short qpl[64 * 256];
  __shared__ short ctl[64 * 256];
  __shared__ float dgs[64];
  __shared__ float ks_l[MM];
  __shared__ float wred[4][64];
  __shared__ float mx_l[64];
  __shared__ float inv_l[64];
  short8v pf[4][2];
#pragma unroll
  for (int mt = 0; mt < 4; mt++)
#pragma unroll
    for (int s = 0; s < 2; s++) {
      int m = w * 64 + mt * 16 + fr;
      const float* src = P + m * 64 + s * 32 + kc * 8;
      float4 f0 = *(const float4*)src;
      float4 f1 = *(const float4*)(src + 4);
      short8v pv;
      pv[0] = f2bs(f0.x); pv[1] = f2bs(f0.y); pv[2] = f2bs(f0.z); pv[3] = f2bs(f0.w);
      pv[4] = f2bs(f1.x); pv[5] = f2bs(f1.y); pv[6] = f2bs(f1.z); pv[7] = f2bs(f1.w);
      pf[mt][s] = pv;
    }
  ks_l[t] = ksum[bh * MM + t];
  {
    int rr = t >> 2, j4 = t & 3;
    size_t gq = ((size_t)(b * NN) + n0 + rr) * QLD + hh * 64 + j4 * 16;
    short8v q0 = *(const short8v*)(q + gq);
    short8v q1 = *(const short8v*)(q + gq + 8);
    *(short8v*)(qsl + rr * 64 + (((2 * j4) ^ (rr & 7)) << 3)) = q0;
    *(short8v*)(qsl + rr * 64 + (((2 * j4 + 1) ^ (rr & 7)) << 3)) = q1;
    float s2 = 0.f;
#pragma unroll
    for (int ii = 0; ii < 8; ii++) {
      float a = bs2f(q0[ii]), c = bs2f(q1[ii]);
      s2 += a * a + c * c;
    }
    s2 += __shfl_down(s2, 2); s2 += __shfl_down(s2, 1);
    if (j4 == 0) dgs[rr] = 0.0625f * s2;
  }
#pragma unroll
  for (int i = 0; i < 8; i++) {
    int e = i * 256 + t;
    int d = e >> 5, c = e & 31;
    short8v cv = *(const short8v*)(ctxT + ((size_t)bh * 64 + d) * 256 + c * 8);
    *(short8v*)(ctl + d * 256 + ((c ^ (d & 7)) << 3)) = cv;
  }
  __syncthreads();
  f32x4 z4 = {0.f, 0.f, 0.f, 0.f};
  f32x4 accd[4][4];
#pragma unroll
  for (int i = 0; i < 4; i++)
#pragma unroll
    for (int j = 0; j < 4; j++) accd[i][j] = z4;
#pragma unroll
  for (int s = 0; s < 2; s++) {
    short8v afr[4];
#pragma unroll
    for (int nt = 0; nt < 4; nt++) {
      int rr = nt * 16 + fr;
      afr[nt] = *(const short8v*)(qsl + rr * 64 + (((s * 4 + kc) ^ (rr & 7)) << 3));
    }
#pragma unroll
    for (int mt = 0; mt < 4; mt++)
#pragma unroll
      for (int nt = 0; nt < 4; nt++)
        accd[nt][mt] = __builtin_amdgcn_mfma_f32_16x16x32_bf16(afr[nt], pf[mt][s], accd[nt][mt], 0, 0, 0);
  }
#pragma unroll
  for (int i = 0; i < 4; i++)
#pragma unroll
    for (int j = 0; j < 4; j++) accd[i][j] = accd[i][j] * DN_;
  {
    float pmx[16];
#pragma unroll
    for (int nt = 0; nt < 4; nt++)
#pragma unroll
      for (int ri = 0; ri < 4; ri++) {
        float m_ = fmaxf(fmaxf(accd[nt][0][ri], accd[nt][1][ri]),
                         fmaxf(accd[nt][2][ri], accd[nt][3][ri]));
#pragma unroll
        for (int o = 1; o < 16; o <<= 1) m_ = fmaxf(m_, __shfl_xor(m_, o));
        pmx[nt * 4 + ri] = m_;
      }
    if (fr == 0) {
#pragma unroll
      for (int nt = 0; nt < 4; nt++)
#pragma unroll
        for (int ri = 0; ri < 4; ri++)
          wred[w][nt * 16 + kc * 4 + ri] = pmx[nt * 4 + ri];
    }
  }
  __syncthreads();
  if (t < 64)
    mx_l[t] = fmaxf(fmaxf(wred[0][t], wred[1][t]), fmaxf(wred[2][t], wred[3][t]));
  __syncthreads();
  {
    float sp[16];
#pragma unroll
    for (int i = 0; i < 16; i++) sp[i] = 0.f;
#pragma unroll
    for (int nt = 0; nt < 4; nt++)
#pragma unroll
      for (int mt = 0; mt < 4; mt++)
#pragma unroll
        for (int ri = 0; ri < 4; ri++) {
          int n = nt * 16 + kc * 4 + ri;
          int m = w * 64 + mt * 16 + fr;
          float kpv = RATIO_ * (__expf(accd[nt][mt][ri] - dgs[n] - mx_l[n]) + KEPS_);
          sp[nt * 4 + ri] += kpv * ks_l[m];
          int c = m >> 3;
          qpl[n * 256 + ((c ^ (n & 7)) << 3) + (m & 7)] = f2bs(kpv);
        }
#pragma unroll
    for (int i = 0; i < 16; i++) {
#pragma unroll
      for (int o = 1; o < 16; o <<= 1) sp[i] += __shfl_xor(sp[i], o);
    }
    if (fr == 0) {
#pragma unroll
      for (int nt = 0; nt < 4; nt++)
#pragma unroll
        for (int ri = 0; ri < 4; ri++)
          wred[w][nt * 16 + kc * 4 + ri] = sp[nt * 4 + ri];
    }
  }
  __syncthreads();
  if (t < 64)
    inv_l[t] = 1.f / (wred[0][t] + wred[1][t] + wred[2][t] + wred[3][t]);
  __syncthreads();
  f32x4 acc2[4];
#pragma unroll
  for (int dt = 0; dt < 4; dt++) acc2[dt] = z4;
  int nrow = w * 16 + fr;
#pragma unroll
  for (int ks = 0; ks < 8; ks++) {
    int c = ks * 4 + kc;
    short8v aq = *(const short8v*)(qpl + nrow * 256 + ((c ^ (nrow & 7)) << 3));
#pragma unroll
    for (int dt = 0; dt < 4; dt++) {
      int d = dt * 16 + fr;
      short8v bc = *(const short8v*)(ctl + d * 256 + ((c ^ (d & 7)) << 3));
      acc2[dt] = __builtin_amdgcn_mfma_f32_16x16x32_bf16(aq, bc, acc2[dt], 0, 0, 0);
    }
  }
#pragma unroll
  for (int dt = 0; dt < 4; dt++)
#pragma unroll
    for (int ri = 0; ri < 4; ri++) {
      int n = w * 16 + kc * 4 + ri;
      int d = dt * 16 + fr;
      attn[((size_t)(b * NN) + n0 + n) * DDIM + hh * 64 + d] =
          __float2bfloat16(acc2[dt][ri] * inv_l[n]);
    }
}

// ---------------------------------------------------------------- mean over N, two-stage
__global__ __launch_bounds__(256) void k_mean1(const float* __restrict__ h,
                                               float* __restrict__ part) {
  int c = blockIdx.x >> 2, b = blockIdx.x & 3;
  int t = threadIdx.x;
  float s0 = 0.f, s1 = 0.f, s2 = 0.f, s3 = 0.f;
  for (int n = c * 32; n < c * 32 + 32; n++) {
    float4 f = *(const float4*)&h[((size_t)b * NN + n) * DDIM + t * 4];
    s0 += f.x; s1 += f.y; s2 += f.z; s3 += f.w;
  }
  float* p = part + (size_t)c * (BB * DDIM) + b * DDIM + t * 4;
  p[0] = s0; p[1] = s1; p[2] = s2; p[3] = s3;
}
__global__ __launch_bounds__(256) void k_mean2(const float* __restrict__ part,
                                               float* __restrict__ out) {
  int idx = blockIdx.x * 256 + threadIdx.x;
  float s = 0.f;
  for (int c = 0; c < 64; c++) s += part[(size_t)c * (BB * DDIM) + idx];
  out[idx] = s * (1.f / NN);
}

// ================================================================ host
extern "C" void kernel_launch(void* const* d_in, const int* in_sizes, int n_in,
                              void* d_out, int out_size, void* d_ws, size_t ws_size,
                              hipStream_t stream) {
  static const long long EXP[21] = {
      8192, 8192, 32768000, 2097152, 4096, 4096,
      4194304, 4096, 4194304, 4096, 4194304, 4096, 4194304, 4096,
      65536, 4096, 4096, 16777216, 16384, 16777216, 4096
  };
  const size_t NEED_WS = 197559552;  // bytes (<= 205.6MB proven in round 5)
  float sentinel = 0.f;
  if (n_in != 21) {
    sentinel = 100000.f + 100.f * (float)n_in;
  } else {
    for (int i = 0; i < 21; i++)
      if ((long long)in_sizes[i] != EXP[i]) { sentinel = 1000.f + 100.f * i; break; }
  }
  if (sentinel == 0.f && out_size != BB * DDIM) sentinel = 6000.f;
  if (sentinel == 0.f && ws_size < NEED_WS) {
    float units = (float)(ws_size / (32ull << 20));
    if (units > 40.f) units = 40.f;
    sentinel = 5000.f + 100.f * units;
  }
  if (sentinel != 0.f) {
    k_sentinel<<<16, 256, 0, stream>>>((float*)d_out, sentinel);
    return;
  }

  const int* x = (const int*)d_in[0];
  const float* tok  = (const float*)d_in[2];
  const float* pos  = (const float*)d_in[3];
  const float* ln1g = (const float*)d_in[4];
  const float* ln1b = (const float*)d_in[5];
  const float* wq   = (const float*)d_in[6];
  const float* bq   = (const float*)d_in[7];
  const float* wk   = (const float*)d_in[8];
  const float* bk   = (const float*)d_in[9];
  const float* wv   = (const float*)d_in[10];
  const float* bv   = (const float*)d_in[11];
  const float* wo   = (const float*)d_in[12];
  const float* bo   = (const float*)d_in[13];
  const float* proj = (const float*)d_in[14];
  const float* ln2g = (const float*)d_in[15];
  const float* ln2b = (const float*)d_in[16];
  const float* w1   = (const float*)d_in[17];
  const float* b1   = (const float*)d_in[18];
  const float* w2   = (const float*)d_in[19];
  const float* b2   = (const float*)d_in[20];

  const int BN = BB * NN;                    // 8192
  const size_t SZ = (size_t)BN * DDIM;       // 8,388,608 floats
  const size_t MEG = 1048576;
  float* ws    = (float*)d_ws;
  float* h     = ws;                          // SZ f32
  u16* qkvb    = (u16*)(ws + SZ);             // [8192][3072] bf16
  __hip_bfloat16* zb   = (__hip_bfloat16*)(ws + 4 * SZ);       // SZ bf16
  float* ctx   = ws + 4 * SZ + SZ / 2;        // ctxT bf16 region
  float* ksum  = ctx + (size_t)BB * HH * MM * DH;
  float* bmaxp = ksum + BB * HH * MM;
  float* bcat  = bmaxp + 4096;                // 3072 f32
  float* mxp   = bmaxp + BB * HH * 128;
  __hip_bfloat16* wt = (__hip_bfloat16*)(mxp + 64);            // 12M bf16
  float* ctxp  = (float*)(wt + 12 * MEG);     // 4 x 1,048,576 f32 partials
  float* esb   = ctxp + 4 * MEG;              // 64*4*256
  float* mxcb  = esb + 65536;                 // 512 (bh x chunk x mh)
  float* svcb  = mxcb + 512;                  // 64*4*64
  u16* ctxT    = (u16*)ctx;
  __hip_bfloat16* ff1b = (__hip_bfloat16*)qkvb;   // overlay (qkv dead during FFN)
  __hip_bfloat16* zab  = (__hip_bfloat16*)ctxp;   // overlay (ctxp dead after ctxred)
  float* meanp = ctxp;

  k_embed_ln<<<BN, 256, 0, stream>>>(x, tok, pos, ln1g, ln1b, h, zb);

  for (int l = 0; l < LL; l++) {
    const float* Wq = wq + (size_t)l * DDIM * DDIM;
    const float* Wk = wk + (size_t)l * DDIM * DDIM;
    const float* Wv = wv + (size_t)l * DDIM * DDIM;
    const float* Wo = wo + (size_t)l * DDIM * DDIM;
    const float* W1 = w1 + (size_t)l * DDIM * FDIM;
    const float* W2 = w2 + (size_t)l * FDIM * DDIM;
    const float* Pl = proj + (size_t)l * MM * DH;
    __hip_bfloat16* wtq = wt;             // [3072][1024] concatenated q|k|v
    __hip_bfloat16* wto = wt + 3 * MEG;
    __hip_bfloat16* wt1 = wt + 4 * MEG;
    __hip_bfloat16* wt2 = wt + 8 * MEG;

    k_wtall<<<3084, 256, 0, stream>>>(Wq, Wk, Wv, Wo, W1, W2,
                                      bq + l * DDIM, bk + l * DDIM, bv + l * DDIM,
                                      wt, bcat);

    if (l > 0)
      k_ln<<<BN, 256, 0, stream>>>(h, ln1g + l * DDIM, ln1b + l * DDIM, zb);

    // fused QKV GEMM on 256^2 tiles: (12, 32) = 384 blocks
    dim3 gQKV(QLD / 256, BN / 256);
    k_gemm_mfma256<false, false><<<gQKV, 512, 0, stream>>>(
        (const u16*)zb, (const u16*)wtq, bcat, qkvb, BN, DDIM, QLD);

    k_kv<<<BB * HH * 8, 256, 0, stream>>>(qkvb + 1024, qkvb + 2048, Pl,
                                          esb, mxcb, svcb, ctxp);
    k_ctxred<<<BB * HH, 256, 0, stream>>>(ctxp, esb, mxcb, svcb, ksum, ctxT);
    k_attn_fused<<<BB * HH * 32, 256, 0, stream>>>(qkvb, Pl, ksum, ctxT, zab);

    dim3 gO(DDIM / 128, BN / 128);    // (8, 64)
    k_gemm_mfma<false, true, true><<<gO, 256, 0, stream>>>(
        (const u16*)zab, (const u16*)wto, bo + l * DDIM, h, h, BN, DDIM, DDIM);

    k_ln<<<BN, 256, 0, stream>>>(h, ln2g + l * DDIM, ln2b + l * DDIM, zb);
    // FFN1 on 256^2 tiles: (16, 32) = 512 blocks
    dim3 g1(FDIM / 256, BN / 256);
    k_gemm_mfma256<true, false><<<g1, 512, 0, stream>>>(
        (const u16*)zb, (const u16*)wt1, b1 + l * FDIM, ff1b, BN, DDIM, FDIM);
    dim3 g2(DDIM / 128, BN / 128);    // (8, 64)
    k_gemm_mfma<false, true, true><<<g2, 256, 0, stream>>>(
        (const u16*)ff1b, (const u16*)wt2, b2 + l * DDIM, h, h, BN, FDIM, DDIM);
  }

  k_mean1<<<256, 256, 0, stream>>>(h, meanp);
  k_mean2<<<16, 256, 0, stream>>>(meanp, (float*)d_out);
}

// Round 17
// 1821.812 us; speedup vs baseline: 1.0333x; 1.0333x over previous
//
#include <hip/hip_runtime.h>
#include <hip/hip_bf16.h>

typedef unsigned short u16;
typedef unsigned int u32;
typedef __attribute__((ext_vector_type(8))) short short8v;
typedef __attribute__((ext_vector_type(4))) float f32x4;

// Problem dims
#define BB    4
#define NN    2048
#define DDIM  1024
#define HH    16
#define DH    64
#define MM    256
#define FDIM  4096
#define LL    4
#define QLD   3072   // fused qkv row stride

static constexpr float DN_    = 0.35355339059327373f;  // 64^-0.25
static constexpr float RATIO_ = 0.0625f;               // 256^-0.5
static constexpr float KEPS_  = 1e-4f;

__device__ __forceinline__ short f2bs(float f) {
  __hip_bfloat16 h = __float2bfloat16(f);
  return *(short*)&h;
}
__device__ __forceinline__ float bs2f(short s) {
  return __uint_as_float(((unsigned)(u16)s) << 16);
}
// A&S 7.1.26 erf, abs err <= 1.5e-7 (<< bf16 ulp)
__device__ __forceinline__ float erf_fast(float x) {
  float ax = fabsf(x);
  float t = 1.f / (1.f + 0.3275911f * ax);
  float y = t * (0.254829592f + t * (-0.284496736f + t * (1.421413741f +
            t * (-1.453152027f + t * 1.061405429f))));
  float r = 1.f - y * __expf(-ax * ax);
  return copysignf(r, x);
}

// async global->LDS 16B: LDS dest wave-uniform base + lane*16
__device__ __forceinline__ void gload_lds16(const void* g, void* l) {
  __builtin_amdgcn_global_load_lds(
      (const __attribute__((address_space(1))) u32*)g,
      (__attribute__((address_space(3))) u32*)l, 16, 0, 0);
}

// ---------------------------------------------------------------- diagnostics
__global__ __launch_bounds__(256) void k_sentinel(float* __restrict__ out, float val) {
  int i = blockIdx.x * 256 + threadIdx.x;
  if (i < BB * DDIM) out[i] = val;
}

// ---------------------------------------------------------------- embed + LN1(layer0) fused
__global__ __launch_bounds__(256) void k_embed_ln(const int* __restrict__ x,
    const float* __restrict__ tok, const float* __restrict__ pos,
    const float* __restrict__ g, const float* __restrict__ b,
    float* __restrict__ h, __hip_bfloat16* __restrict__ zb) {
  int r = blockIdx.x, t = threadIdx.x;
  int n = r & (NN - 1);
  int id = x[r];
  const float* tr = tok + (size_t)id * DDIM;
  const float* pr = pos + (size_t)n * DDIM;
  float* hr = h + (size_t)r * DDIM;
  float v[4], s = 0.f, s2 = 0.f;
#pragma unroll
  for (int i = 0; i < 4; i++) {
    int d = t + i * 256;
    v[i] = tr[d] + pr[d];
    hr[d] = v[i];
    s += v[i]; s2 += v[i] * v[i];
  }
#pragma unroll
  for (int o = 32; o > 0; o >>= 1) { s += __shfl_down(s, o); s2 += __shfl_down(s2, o); }
  __shared__ float ws[8];
  int wid = t >> 6, lane = t & 63;
  if (lane == 0) { ws[wid] = s; ws[4 + wid] = s2; }
  __syncthreads();
  s = ws[0] + ws[1] + ws[2] + ws[3];
  s2 = ws[4] + ws[5] + ws[6] + ws[7];
  float mu = s * (1.f / DDIM);
  float var = s2 * (1.f / DDIM) - mu * mu;
  float rstd = rsqrtf(var + 1e-5f);
  __hip_bfloat16* orow = zb + (size_t)r * DDIM;
#pragma unroll
  for (int i = 0; i < 4; i++) {
    int d = t + i * 256;
    orow[d] = __float2bfloat16((v[i] - mu) * rstd * g[d] + b[d]);
  }
}

// ---------------------------------------------------------------- layernorm (bf16 out)
__global__ __launch_bounds__(256) void k_ln(const float* __restrict__ in,
    const float* __restrict__ g, const float* __restrict__ b,
    __hip_bfloat16* __restrict__ out) {
  int r = blockIdx.x, t = threadIdx.x;
  const float* xr = in + (size_t)r * DDIM;
  float v[4], s = 0.f, s2 = 0.f;
#pragma unroll
  for (int i = 0; i < 4; i++) {
    v[i] = xr[t + i * 256];
    s += v[i]; s2 += v[i] * v[i];
  }
#pragma unroll
  for (int o = 32; o > 0; o >>= 1) { s += __shfl_down(s, o); s2 += __shfl_down(s2, o); }
  __shared__ float ws[8];
  int wid = t >> 6, lane = t & 63;
  if (lane == 0) { ws[wid] = s; ws[4 + wid] = s2; }
  __syncthreads();
  s = ws[0] + ws[1] + ws[2] + ws[3];
  s2 = ws[4] + ws[5] + ws[6] + ws[7];
  float mu = s * (1.f / DDIM);
  float var = s2 * (1.f / DDIM) - mu * mu;
  float rstd = rsqrtf(var + 1e-5f);
  __hip_bfloat16* orow = out + (size_t)r * DDIM;
#pragma unroll
  for (int i = 0; i < 4; i++) {
    int d = t + i * 256;
    orow[d] = __float2bfloat16((v[i] - mu) * rstd * g[d] + b[d]);
  }
}

// ---------------------------------------------------------------- ALL weight transposes + bias concat, one dispatch
__global__ __launch_bounds__(256) void k_wtall(const float* __restrict__ Wq,
    const float* __restrict__ Wk, const float* __restrict__ Wv,
    const float* __restrict__ Wo, const float* __restrict__ W1,
    const float* __restrict__ W2, const float* __restrict__ bq,
    const float* __restrict__ bk, const float* __restrict__ bv,
    __hip_bfloat16* __restrict__ wt, float* __restrict__ bcat) {
  int id = blockIdx.x;
  int t = threadIdx.x;
  if (id >= 3072) {                     // bias concat: 12 blocks
    int i = (id - 3072) * 256 + t;
    bcat[i] = i < 1024 ? bq[i] : (i < 2048 ? bk[i - 1024] : bv[i - 2048]);
    return;
  }
  const float* W;
  __hip_bfloat16* Wt;
  int K, N, n0, k0;
  if (id < 1024) {                      // Wq|Wk|Wv|Wo: 256 tiles each
    int which = id >> 8, local = id & 255;
    W = which == 0 ? Wq : which == 1 ? Wk : which == 2 ? Wv : Wo;
    Wt = wt + (size_t)which * 1048576;
    K = 1024; N = 1024;
    n0 = (local & 15) * 64; k0 = (local >> 4) * 64;
  } else if (id < 2048) {               // W1: K=1024, N=4096
    int local = id - 1024;
    W = W1; Wt = wt + (size_t)4 * 1048576;
    K = 1024; N = 4096;
    n0 = (local & 63) * 64; k0 = (local >> 6) * 64;
  } else {                              // W2: K=4096, N=1024
    int local = id - 2048;
    W = W2; Wt = wt + (size_t)8 * 1048576;
    K = 4096; N = 1024;
    n0 = (local & 15) * 64; k0 = (local >> 4) * 64;
  }
  __shared__ float tl[64][68];
#pragma unroll
  for (int i = 0; i < 4; i++) {
    int kl = (t >> 4) + i * 16;
    float4 f = *(const float4*)&W[(size_t)(k0 + kl) * N + n0 + (t & 15) * 4];
    tl[kl][(t & 15) * 4 + 0] = f.x;
    tl[kl][(t & 15) * 4 + 1] = f.y;
    tl[kl][(t & 15) * 4 + 2] = f.z;
    tl[kl][(t & 15) * 4 + 3] = f.w;
  }
  __syncthreads();
  int nl = t >> 2;
#pragma unroll
  for (int i = 0; i < 4; i++) {
    int kl = (t & 3) * 4 + i * 16;
    size_t ob = (size_t)(n0 + nl) * K + k0 + kl;
    Wt[ob + 0] = __float2bfloat16(tl[kl + 0][nl]);
    Wt[ob + 1] = __float2bfloat16(tl[kl + 1][nl]);
    Wt[ob + 2] = __float2bfloat16(tl[kl + 2][nl]);
    Wt[ob + 3] = __float2bfloat16(tl[kl + 3][nl]);
  }
}

// ---------------------------------------------------------------- MFMA GEMM 128x128 (r15, verified 1.822ms)
template <bool GELU, bool RES, bool OUTF32>
__global__ __launch_bounds__(256) void k_gemm_mfma(
    const u16* __restrict__ A, const u16* __restrict__ Bt,
    const float* __restrict__ bias, const float* __restrict__ Cin,
    void* __restrict__ Cout, int M, int K, int Nc) {
  __shared__ short As[2][128 * 32];
  __shared__ short Bs[2][128 * 32];
  int t = threadIdx.x;
  int lane = t & 63, w = t >> 6;
  int wr = w >> 1, wc = w & 1;
  int nwg = gridDim.x * gridDim.y;
  int id = blockIdx.y * gridDim.x + blockIdx.x;
  int swz = (id & 7) * (nwg >> 3) + (id >> 3);
  int bx = swz % gridDim.x, by = swz / gridDim.x;
  int row0 = by * 128, col0 = bx * 128;
  f32x4 acc[4][4];
  f32x4 z4 = {0.f, 0.f, 0.f, 0.f};
#pragma unroll
  for (int i = 0; i < 4; i++)
#pragma unroll
    for (int j = 0; j < 4; j++) acc[i][j] = z4;
  int fr = lane & 15;
  int fc = lane >> 4;
  int offA[4], offB[4];
#pragma unroll
  for (int f = 0; f < 4; f++) {
    int ra = wr * 64 + f * 16 + fr;
    offA[f] = ra * 32 + (fc ^ ((ra >> 1) & 3)) * 8;
    int rb = wc * 64 + f * 16 + fr;
    offB[f] = rb * 32 + (fc ^ ((rb >> 1) & 3)) * 8;
  }
  int c0 = t, c1 = 256 + t;
  int r0 = c0 >> 2, cl0 = (c0 & 3) ^ ((r0 >> 1) & 3);
  int r1 = c1 >> 2, cl1 = (c1 & 3) ^ ((r1 >> 1) & 3);
  const u16* pA0 = A + (size_t)(row0 + r0) * K + cl0 * 8;
  const u16* pA1 = A + (size_t)(row0 + r1) * K + cl1 * 8;
  const u16* pB0 = Bt + (size_t)(col0 + r0) * K + cl0 * 8;
  const u16* pB1 = Bt + (size_t)(col0 + r1) * K + cl1 * 8;

  auto STG = [&](short* Ab, short* Bb) {
    gload_lds16(pA0, Ab + c0 * 8);
    gload_lds16(pA1, Ab + c1 * 8);
    gload_lds16(pB0, Bb + c0 * 8);
    gload_lds16(pB1, Bb + c1 * 8);
    pA0 += 32; pA1 += 32; pB0 += 32; pB1 += 32;
  };
  auto COMPUTE = [&](const short* Ab, const short* Bb) {
    short8v af[4], bfr[4];
#pragma unroll
    for (int f = 0; f < 4; f++) {
      af[f] = *(const short8v*)(Ab + offA[f]);
      bfr[f] = *(const short8v*)(Bb + offB[f]);
    }
#pragma unroll
    for (int fi = 0; fi < 4; fi++)
#pragma unroll
      for (int fj = 0; fj < 4; fj++)
        acc[fi][fj] = __builtin_amdgcn_mfma_f32_16x16x32_bf16(
            af[fi], bfr[fj], acc[fi][fj], 0, 0, 0);
  };

  int KT = K >> 5;            // even at all call sites
  STG(As[0], Bs[0]);
  __syncthreads();
  for (int kt = 0; kt < KT - 2; kt += 2) {
    STG(As[1], Bs[1]);
    COMPUTE(As[0], Bs[0]);
    __syncthreads();
    STG(As[0], Bs[0]);
    COMPUTE(As[1], Bs[1]);
    __syncthreads();
  }
  STG(As[1], Bs[1]);
  COMPUTE(As[0], Bs[0]);
  __syncthreads();
  COMPUTE(As[1], Bs[1]);
#pragma unroll
  for (int fi = 0; fi < 4; fi++) {
#pragma unroll
    for (int fj = 0; fj < 4; fj++) {
#pragma unroll
      for (int ri = 0; ri < 4; ri++) {
        int row = row0 + wr * 64 + fi * 16 + (lane >> 4) * 4 + ri;
        int col = col0 + wc * 64 + fj * 16 + fr;
        float vv = acc[fi][fj][ri] + bias[col];
        if (GELU) vv = 0.5f * vv * (1.f + erf_fast(vv * 0.70710678118f));
        if (RES) vv += Cin[(size_t)row * Nc + col];
        if (OUTF32) ((float*)Cout)[(size_t)row * Nc + col] = vv;
        else ((__hip_bfloat16*)Cout)[(size_t)row * Nc + col] = __float2bfloat16(vv);
      }
    }
  }
}

// ---------------------------------------------------------------- fused key-side, MFMA, online-max, m-split
__global__ __launch_bounds__(256) void k_kv(const u16* __restrict__ kq,
    const u16* __restrict__ vq, const float* __restrict__ P,
    float* __restrict__ es, float* __restrict__ mxc, float* __restrict__ svc,
    float* __restrict__ ctx_part) {
  int bh = blockIdx.x >> 3;
  int chunk = (blockIdx.x >> 1) & 3;
  int mh = blockIdx.x & 1;
  int b = bh >> 4, hh = bh & 15;
  int t = threadIdx.x, lane = t & 63, w = t >> 6;
  int fr = lane & 15, kc = lane >> 4;
  __shared__ short Pl[128 * 64];
  __shared__ short ksl[32 * 64];
  __shared__ short vtl[64 * 32];
  __shared__ short kpl[128 * 32];
  __shared__ float dgs[32];
  __shared__ float wredk[4];
  __shared__ float svl[32][64];
#pragma unroll
  for (int i = 0; i < 4; i++) {
    int e = i * 256 + t;
    int m = e >> 3, j = e & 7;
    const float* src = P + (size_t)(mh * 128 + m) * 64 + j * 8;
    float4 f0 = *(const float4*)src;
    float4 f1 = *(const float4*)(src + 4);
    short* dst = Pl + m * 64 + ((j ^ (m & 7)) << 3);
    dst[0] = f2bs(f0.x); dst[1] = f2bs(f0.y); dst[2] = f2bs(f0.z); dst[3] = f2bs(f0.w);
    dst[4] = f2bs(f1.x); dst[5] = f2bs(f1.y); dst[6] = f2bs(f1.z); dst[7] = f2bs(f1.w);
  }
  f32x4 z4 = {0.f, 0.f, 0.f, 0.f};
  f32x4 accc[2][4];
#pragma unroll
  for (int i = 0; i < 2; i++)
#pragma unroll
    for (int j = 0; j < 4; j++) accc[i][j] = z4;
  float ksp[2] = {0.f, 0.f};
  float svp[8] = {0.f, 0.f, 0.f, 0.f, 0.f, 0.f, 0.f, 0.f};
  float m_run = -3e38f;
  int r8 = t >> 3, j8 = t & 7;
  for (int tile = 0; tile < 16; ++tile) {
    int n0 = chunk * 512 + tile * 32;
    __syncthreads();
    {
      size_t gk = ((size_t)(b * NN) + n0 + r8) * QLD + hh * 64 + j8 * 8;
      short8v k8 = *(const short8v*)(kq + gk);
      *(short8v*)(ksl + r8 * 64 + ((j8 ^ (r8 & 7)) << 3)) = k8;
      float s2 = 0.f;
#pragma unroll
      for (int ii = 0; ii < 8; ii++) { float rv = bs2f(k8[ii]); s2 += rv * rv; }
      s2 += __shfl_down(s2, 4); s2 += __shfl_down(s2, 2); s2 += __shfl_down(s2, 1);
      if (j8 == 0) dgs[r8] = 0.0625f * s2;
      short8v v8 = *(const short8v*)(vq + gk);
#pragma unroll
      for (int ii = 0; ii < 8; ii++) {
        int d = j8 * 8 + ii;
        vtl[d * 32 + (((r8 >> 3) ^ ((d >> 1) & 3)) << 3) + (r8 & 7)] = v8[ii];
        svp[ii] += bs2f(v8[ii]);
      }
    }
    __syncthreads();
    f32x4 accd[2][2];
#pragma unroll
    for (int nt = 0; nt < 2; nt++)
#pragma unroll
      for (int mt = 0; mt < 2; mt++) accd[nt][mt] = z4;
#pragma unroll
    for (int s = 0; s < 2; s++) {
      short8v afr[2];
#pragma unroll
      for (int nt = 0; nt < 2; nt++) {
        int rr = nt * 16 + fr;
        afr[nt] = *(const short8v*)(ksl + rr * 64 + (((s * 4 + kc) ^ (rr & 7)) << 3));
      }
#pragma unroll
      for (int mt = 0; mt < 2; mt++) {
        int ml = w * 32 + mt * 16 + fr;
        short8v bfp = *(const short8v*)(Pl + ml * 64 + (((s * 4 + kc) ^ (ml & 7)) << 3));
#pragma unroll
        for (int nt = 0; nt < 2; nt++)
          accd[nt][mt] = __builtin_amdgcn_mfma_f32_16x16x32_bf16(afr[nt], bfp, accd[nt][mt], 0, 0, 0);
      }
    }
    float tm = -3e38f;
#pragma unroll
    for (int nt = 0; nt < 2; nt++)
#pragma unroll
      for (int mt = 0; mt < 2; mt++) {
        accd[nt][mt] = accd[nt][mt] * DN_;
        tm = fmaxf(tm, fmaxf(fmaxf(accd[nt][mt][0], accd[nt][mt][1]),
                             fmaxf(accd[nt][mt][2], accd[nt][mt][3])));
      }
#pragma unroll
    for (int o = 32; o > 0; o >>= 1) tm = fmaxf(tm, __shfl_xor(tm, o));
    if (lane == 0) wredk[w] = tm;
    __syncthreads();
    float bm = fmaxf(fmaxf(wredk[0], wredk[1]), fmaxf(wredk[2], wredk[3]));
    float nm = fmaxf(m_run, bm);
    float fac = __expf(m_run - nm);
#pragma unroll
    for (int mt = 0; mt < 2; mt++) {
      ksp[mt] *= fac;
#pragma unroll
      for (int dt = 0; dt < 4; dt++) accc[mt][dt] = accc[mt][dt] * fac;
    }
    m_run = nm;
#pragma unroll
    for (int nt = 0; nt < 2; nt++)
#pragma unroll
      for (int mt = 0; mt < 2; mt++)
#pragma unroll
        for (int ri = 0; ri < 4; ri++) {
          int n = nt * 16 + kc * 4 + ri;
          int ml = w * 32 + mt * 16 + fr;
          float kpv = __expf(accd[nt][mt][ri] - dgs[n] - m_run);
          ksp[mt] += kpv;
          kpl[ml * 32 + (((n >> 3) ^ ((ml >> 1) & 3)) << 3) + (n & 7)] = f2bs(kpv);
        }
    short8v bvv[4];
#pragma unroll
    for (int dt = 0; dt < 4; dt++) {
      int d = dt * 16 + fr;
      bvv[dt] = *(const short8v*)(vtl + d * 32 + ((kc ^ ((d >> 1) & 3)) << 3));
    }
#pragma unroll
    for (int mt = 0; mt < 2; mt++) {
      int ml = w * 32 + mt * 16 + fr;
      short8v ak = *(const short8v*)(kpl + ml * 32 + ((kc ^ ((ml >> 1) & 3)) << 3));
#pragma unroll
      for (int dt = 0; dt < 4; dt++)
        accc[mt][dt] = __builtin_amdgcn_mfma_f32_16x16x32_bf16(ak, bvv[dt], accc[mt][dt], 0, 0, 0);
    }
  }
#pragma unroll
  for (int mt = 0; mt < 2; mt++) {
    float vv = ksp[mt];
    vv += __shfl_xor(vv, 16);
    vv += __shfl_xor(vv, 32);
    if (lane < 16)
      es[((size_t)bh * 4 + chunk) * MM + mh * 128 + w * 32 + mt * 16 + lane] = vv;
  }
  if (t == 0) mxc[((size_t)bh * 4 + chunk) * 2 + mh] = m_run;
#pragma unroll
  for (int ii = 0; ii < 8; ii++) svl[r8][j8 * 8 + ii] = svp[ii];
  __syncthreads();
  if (mh == 0 && t < 64) {
    float s = 0.f;
#pragma unroll
    for (int r = 0; r < 32; r++) s += svl[r][t];
    svc[((size_t)bh * 4 + chunk) * 64 + t] = s;
  }
  size_t base = ((size_t)(chunk * 64 + bh)) * MM * DH;
#pragma unroll
  for (int mt = 0; mt < 2; mt++)
#pragma unroll
    for (int dt = 0; dt < 4; dt++)
#pragma unroll
      for (int ri = 0; ri < 4; ri++) {
        int mg = mh * 128 + w * 32 + mt * 16 + kc * 4 + ri;
        int d = dt * 16 + fr;
        ctx_part[base + mg * 64 + d] = accc[mt][dt][ri];
      }
}

// ---------------------------------------------------------------- combine 4chunks x 2mhalves
__global__ __launch_bounds__(256) void k_ctxred(const float* __restrict__ part,
    const float* __restrict__ es, const float* __restrict__ mxc,
    const float* __restrict__ svc, float* __restrict__ ksum,
    u16* __restrict__ ctxT) {
  int bh = blockIdx.x, t = threadIdx.x;
  __shared__ float tl[64][65];
  __shared__ float facs[8];
  __shared__ float svg[64];
  float mg = -3e38f;
#pragma unroll
  for (int i = 0; i < 8; i++) mg = fmaxf(mg, mxc[(size_t)bh * 8 + i]);
  if (t < 8) facs[t] = __expf(mxc[(size_t)bh * 8 + t] - mg);
  if (t >= 64 && t < 128) {
    int d = t - 64;
    svg[d] = svc[((size_t)bh * 4 + 0) * 64 + d] + svc[((size_t)bh * 4 + 1) * 64 + d] +
             svc[((size_t)bh * 4 + 2) * 64 + d] + svc[((size_t)bh * 4 + 3) * 64 + d];
  }
  __syncthreads();
  {
    size_t eb = (size_t)bh * 4 * MM;
    int mhb = t >> 7;
    float s = es[eb + t] * facs[0 * 2 + mhb] + es[eb + MM + t] * facs[1 * 2 + mhb] +
              es[eb + 2 * MM + t] * facs[2 * 2 + mhb] + es[eb + 3 * MM + t] * facs[3 * 2 + mhb];
    ksum[bh * MM + t] = RATIO_ * (s + KEPS_ * 2048.0f);
  }
  const size_t CH = (size_t)64 * MM * DH;
  for (int mt = 0; mt < 4; mt++) {
    int mhb = mt >> 1;
    float f0 = facs[0 * 2 + mhb], f1 = facs[1 * 2 + mhb];
    float f2 = facs[2 * 2 + mhb], f3 = facs[3 * 2 + mhb];
    __syncthreads();
#pragma unroll
    for (int i = 0; i < 16; i++) {
      int e = i * 256 + t;
      int ml = e >> 6, d = e & 63;
      size_t off = (size_t)bh * MM * DH + (size_t)(mt * 64 + ml) * 64 + d;
      float ev = part[off] * f0 + part[CH + off] * f1 +
                 part[2 * CH + off] * f2 + part[3 * CH + off] * f3;
      tl[ml][d] = RATIO_ * (ev + KEPS_ * svg[d]);
    }
    __syncthreads();
#pragma unroll
    for (int i = 0; i < 16; i++) {
      int e = i * 256 + t;
      int d = e >> 6, ml = e & 63;
      ctxT[((size_t)bh * 64 + d) * 256 + mt * 64 + ml] = (u16)f2bs(tl[ml][d]);
    }
  }
}

// ---------------------------------------------------------------- fused query-side, MFMA
__global__ __launch_bounds__(256) void k_attn_fused(const u16* __restrict__ q,
    const float* __restrict__ P, const float* __restrict__ ksum,
    const u16* __restrict__ ctxT, __hip_bfloat16* __restrict__ attn) {
  int bh = blockIdx.x >> 5, rb = blockIdx.x & 31;
  int b = bh >> 4, hh = bh & 15;
  int n0 = rb * 64;
  int t = threadIdx.x, lane = t & 63, w = t >> 6;
  int fr = lane & 15, kc = lane >> 4;
  __shared__ short qsl[64 * 64];
  __shared__ short qpl[64 * 256];
  __shared__ short ctl[64 * 256];
  __shared__ float dgs[64];
  __shared__ float ks_l[MM];
  __shared__ float wred[4][64];
  __shared__ float mx_l[64];
  __shared__ float inv_l[64];
  short8v pf[4][2];
#pragma unroll
  for (int mt = 0; mt < 4; mt++)
#pragma unroll
    for (int s = 0; s < 2; s++) {
      int m = w * 64 + mt * 16 + fr;
      const float* src = P + m * 64 + s * 32 + kc * 8;
      float4 f0 = *(const float4*)src;
      float4 f1 = *(const float4*)(src + 4);
      short8v pv;
      pv[0] = f2bs(f0.x); pv[1] = f2bs(f0.y); pv[2] = f2bs(f0.z); pv[3] = f2bs(f0.w);
      pv[4] = f2bs(f1.x); pv[5] = f2bs(f1.y); pv[6] = f2bs(f1.z); pv[7] = f2bs(f1.w);
      pf[mt][s] = pv;
    }
  ks_l[t] = ksum[bh * MM + t];
  {
    int rr = t >> 2, j4 = t & 3;
    size_t gq = ((size_t)(b * NN) + n0 + rr) * QLD + hh * 64 + j4 * 16;
    short8v q0 = *(const short8v*)(q + gq);
    short8v q1 = *(const short8v*)(q + gq + 8);
    *(short8v*)(qsl + rr * 64 + (((2 * j4) ^ (rr & 7)) << 3)) = q0;
    *(short8v*)(qsl + rr * 64 + (((2 * j4 + 1) ^ (rr & 7)) << 3)) = q1;
    float s2 = 0.f;
#pragma unroll
    for (int ii = 0; ii < 8; ii++) {
      float a = bs2f(q0[ii]), c = bs2f(q1[ii]);
      s2 += a * a + c * c;
    }
    s2 += __shfl_down(s2, 2); s2 += __shfl_down(s2, 1);
    if (j4 == 0) dgs[rr] = 0.0625f * s2;
  }
#pragma unroll
  for (int i = 0; i < 8; i++) {
    int e = i * 256 + t;
    int d = e >> 5, c = e & 31;
    short8v cv = *(const short8v*)(ctxT + ((size_t)bh * 64 + d) * 256 + c * 8);
    *(short8v*)(ctl + d * 256 + ((c ^ (d & 7)) << 3)) = cv;
  }
  __syncthreads();
  f32x4 z4 = {0.f, 0.f, 0.f, 0.f};
  f32x4 accd[4][4];
#pragma unroll
  for (int i = 0; i < 4; i++)
#pragma unroll
    for (int j = 0; j < 4; j++) accd[i][j] = z4;
#pragma unroll
  for (int s = 0; s < 2; s++) {
    short8v afr[4];
#pragma unroll
    for (int nt = 0; nt < 4; nt++) {
      int rr = nt * 16 + fr;
      afr[nt] = *(const short8v*)(qsl + rr * 64 + (((s * 4 + kc) ^ (rr & 7)) << 3));
    }
#pragma unroll
    for (int mt = 0; mt < 4; mt++)
#pragma unroll
      for (int nt = 0; nt < 4; nt++)
        accd[nt][mt] = __builtin_amdgcn_mfma_f32_16x16x32_bf16(afr[nt], pf[mt][s], accd[nt][mt], 0, 0, 0);
  }
#pragma unroll
  for (int i = 0; i < 4; i++)
#pragma unroll
    for (int j = 0; j < 4; j++) accd[i][j] = accd[i][j] * DN_;
  {
    float pmx[16];
#pragma unroll
    for (int nt = 0; nt < 4; nt++)
#pragma unroll
      for (int ri = 0; ri < 4; ri++) {
        float m_ = fmaxf(fmaxf(accd[nt][0][ri], accd[nt][1][ri]),
                         fmaxf(accd[nt][2][ri], accd[nt][3][ri]));
#pragma unroll
        for (int o = 1; o < 16; o <<= 1) m_ = fmaxf(m_, __shfl_xor(m_, o));
        pmx[nt * 4 + ri] = m_;
      }
    if (fr == 0) {
#pragma unroll
      for (int nt = 0; nt < 4; nt++)
#pragma unroll
        for (int ri = 0; ri < 4; ri++)
          wred[w][nt * 16 + kc * 4 + ri] = pmx[nt * 4 + ri];
    }
  }
  __syncthreads();
  if (t < 64)
    mx_l[t] = fmaxf(fmaxf(wred[0][t], wred[1][t]), fmaxf(wred[2][t], wred[3][t]));
  __syncthreads();
  {
    float sp[16];
#pragma unroll
    for (int i = 0; i < 16; i++) sp[i] = 0.f;
#pragma unroll
    for (int nt = 0; nt < 4; nt++)
#pragma unroll
      for (int mt = 0; mt < 4; mt++)
#pragma unroll
        for (int ri = 0; ri < 4; ri++) {
          int n = nt * 16 + kc * 4 + ri;
          int m = w * 64 + mt * 16 + fr;
          float kpv = RATIO_ * (__expf(accd[nt][mt][ri] - dgs[n] - mx_l[n]) + KEPS_);
          sp[nt * 4 + ri] += kpv * ks_l[m];
          int c = m >> 3;
          qpl[n * 256 + ((c ^ (n & 7)) << 3) + (m & 7)] = f2bs(kpv);
        }
#pragma unroll
    for (int i = 0; i < 16; i++) {
#pragma unroll
      for (int o = 1; o < 16; o <<= 1) sp[i] += __shfl_xor(sp[i], o);
    }
    if (fr == 0) {
#pragma unroll
      for (int nt = 0; nt < 4; nt++)
#pragma unroll
        for (int ri = 0; ri < 4; ri++)
          wred[w][nt * 16 + kc * 4 + ri] = sp[nt * 4 + ri];
    }
  }
  __syncthreads();
  if (t < 64)
    inv_l[t] = 1.f / (wred[0][t] + wred[1][t] + wred[2][t] + wred[3][t]);
  __syncthreads();
  f32x4 acc2[4];
#pragma unroll
  for (int dt = 0; dt < 4; dt++) acc2[dt] = z4;
  int nrow = w * 16 + fr;
#pragma unroll
  for (int ks = 0; ks < 8; ks++) {
    int c = ks * 4 + kc;
    short8v aq = *(const short8v*)(qpl + nrow * 256 + ((c ^ (nrow & 7)) << 3));
#pragma unroll
    for (int dt = 0; dt < 4; dt++) {
      int d = dt * 16 + fr;
      short8v bc = *(const short8v*)(ctl + d * 256 + ((c ^ (d & 7)) << 3));
      acc2[dt] = __builtin_amdgcn_mfma_f32_16x16x32_bf16(aq, bc, acc2[dt], 0, 0, 0);
    }
  }
#pragma unroll
  for (int dt = 0; dt < 4; dt++)
#pragma unroll
    for (int ri = 0; ri < 4; ri++) {
      int n = w * 16 + kc * 4 + ri;
      int d = dt * 16 + fr;
      attn[((size_t)(b * NN) + n0 + n) * DDIM + hh * 64 + d] =
          __float2bfloat16(acc2[dt][ri] * inv_l[n]);
    }
}

// ---------------------------------------------------------------- mean over N, two-stage
__global__ __launch_bounds__(256) void k_mean1(const float* __restrict__ h,
                                               float* __restrict__ part) {
  int c = blockIdx.x >> 2, b = blockIdx.x & 3;
  int t = threadIdx.x;
  float s0 = 0.f, s1 = 0.f, s2 = 0.f, s3 = 0.f;
  for (int n = c * 32; n < c * 32 + 32; n++) {
    float4 f = *(const float4*)&h[((size_t)b * NN + n) * DDIM + t * 4];
    s0 += f.x; s1 += f.y; s2 += f.z; s3 += f.w;
  }
  float* p = part + (size_t)c * (BB * DDIM) + b * DDIM + t * 4;
  p[0] = s0; p[1] = s1; p[2] = s2; p[3] = s3;
}
__global__ __launch_bounds__(256) void k_mean2(const float* __restrict__ part,
                                               float* __restrict__ out) {
  int idx = blockIdx.x * 256 + threadIdx.x;
  float s = 0.f;
  for (int c = 0; c < 64; c++) s += part[(size_t)c * (BB * DDIM) + idx];
  out[idx] = s * (1.f / NN);
}

// ================================================================ host
extern "C" void kernel_launch(void* const* d_in, const int* in_sizes, int n_in,
                              void* d_out, int out_size, void* d_ws, size_t ws_size,
                              hipStream_t stream) {
  static const long long EXP[21] = {
      8192, 8192, 32768000, 2097152, 4096, 4096,
      4194304, 4096, 4194304, 4096, 4194304, 4096, 4194304, 4096,
      65536, 4096, 4096, 16777216, 16384, 16777216, 4096
  };
  const size_t NEED_WS = 197559552;  // bytes (<= 205.6MB proven in round 5)
  float sentinel = 0.f;
  if (n_in != 21) {
    sentinel = 100000.f + 100.f * (float)n_in;
  } else {
    for (int i = 0; i < 21; i++)
      if ((long long)in_sizes[i] != EXP[i]) { sentinel = 1000.f + 100.f * i; break; }
  }
  if (sentinel == 0.f && out_size != BB * DDIM) sentinel = 6000.f;
  if (sentinel == 0.f && ws_size < NEED_WS) {
    float units = (float)(ws_size / (32ull << 20));
    if (units > 40.f) units = 40.f;
    sentinel = 5000.f + 100.f * units;
  }
  if (sentinel != 0.f) {
    k_sentinel<<<16, 256, 0, stream>>>((float*)d_out, sentinel);
    return;
  }

  const int* x = (const int*)d_in[0];
  const float* tok  = (const float*)d_in[2];
  const float* pos  = (const float*)d_in[3];
  const float* ln1g = (const float*)d_in[4];
  const float* ln1b = (const float*)d_in[5];
  const float* wq   = (const float*)d_in[6];
  const float* bq   = (const float*)d_in[7];
  const float* wk   = (const float*)d_in[8];
  const float* bk   = (const float*)d_in[9];
  const float* wv   = (const float*)d_in[10];
  const float* bv   = (const float*)d_in[11];
  const float* wo   = (const float*)d_in[12];
  const float* bo   = (const float*)d_in[13];
  const float* proj = (const float*)d_in[14];
  const float* ln2g = (const float*)d_in[15];
  const float* ln2b = (const float*)d_in[16];
  const float* w1   = (const float*)d_in[17];
  const float* b1   = (const float*)d_in[18];
  const float* w2   = (const float*)d_in[19];
  const float* b2   = (const float*)d_in[20];

  const int BN = BB * NN;                    // 8192
  const size_t SZ = (size_t)BN * DDIM;       // 8,388,608 floats
  const size_t MEG = 1048576;
  float* ws    = (float*)d_ws;
  float* h     = ws;                          // SZ f32
  u16* qkvb    = (u16*)(ws + SZ);             // [8192][3072] bf16
  __hip_bfloat16* zb   = (__hip_bfloat16*)(ws + 4 * SZ);       // SZ bf16
  float* ctx   = ws + 4 * SZ + SZ / 2;        // ctxT bf16 region
  float* ksum  = ctx + (size_t)BB * HH * MM * DH;
  float* bmaxp = ksum + BB * HH * MM;
  float* bcat  = bmaxp + 4096;                // 3072 f32
  float* mxp   = bmaxp + BB * HH * 128;
  __hip_bfloat16* wt = (__hip_bfloat16*)(mxp + 64);            // 12M bf16
  float* ctxp  = (float*)(wt + 12 * MEG);     // 4 x 1,048,576 f32 partials
  float* esb   = ctxp + 4 * MEG;              // 64*4*256
  float* mxcb  = esb + 65536;                 // 512 (bh x chunk x mh)
  float* svcb  = mxcb + 512;                  // 64*4*64
  u16* ctxT    = (u16*)ctx;
  __hip_bfloat16* ff1b = (__hip_bfloat16*)qkvb;   // overlay (qkv dead during FFN)
  __hip_bfloat16* zab  = (__hip_bfloat16*)ctxp;   // overlay (ctxp dead after ctxred)
  float* meanp = ctxp;

  k_embed_ln<<<BN, 256, 0, stream>>>(x, tok, pos, ln1g, ln1b, h, zb);

  for (int l = 0; l < LL; l++) {
    const float* Wq = wq + (size_t)l * DDIM * DDIM;
    const float* Wk = wk + (size_t)l * DDIM * DDIM;
    const float* Wv = wv + (size_t)l * DDIM * DDIM;
    const float* Wo = wo + (size_t)l * DDIM * DDIM;
    const float* W1 = w1 + (size_t)l * DDIM * FDIM;
    const float* W2 = w2 + (size_t)l * FDIM * DDIM;
    const float* Pl = proj + (size_t)l * MM * DH;
    __hip_bfloat16* wtq = wt;             // [3072][1024] concatenated q|k|v
    __hip_bfloat16* wto = wt + 3 * MEG;
    __hip_bfloat16* wt1 = wt + 4 * MEG;
    __hip_bfloat16* wt2 = wt + 8 * MEG;

    k_wtall<<<3084, 256, 0, stream>>>(Wq, Wk, Wv, Wo, W1, W2,
                                      bq + l * DDIM, bk + l * DDIM, bv + l * DDIM,
                                      wt, bcat);

    if (l > 0)
      k_ln<<<BN, 256, 0, stream>>>(h, ln1g + l * DDIM, ln1b + l * DDIM, zb);

    dim3 gQKV(QLD / 128, BN / 128);   // (24, 64)
    k_gemm_mfma<false, false, false><<<gQKV, 256, 0, stream>>>(
        (const u16*)zb, (const u16*)wtq, bcat, nullptr, qkvb, BN, DDIM, QLD);

    k_kv<<<BB * HH * 8, 256, 0, stream>>>(qkvb + 1024, qkvb + 2048, Pl,
                                          esb, mxcb, svcb, ctxp);
    k_ctxred<<<BB * HH, 256, 0, stream>>>(ctxp, esb, mxcb, svcb, ksum, ctxT);
    k_attn_fused<<<BB * HH * 32, 256, 0, stream>>>(qkvb, Pl, ksum, ctxT, zab);

    dim3 gO(DDIM / 128, BN / 128);    // (8, 64)
    k_gemm_mfma<false, true, true><<<gO, 256, 0, stream>>>(
        (const u16*)zab, (const u16*)wto, bo + l * DDIM, h, h, BN, DDIM, DDIM);

    k_ln<<<BN, 256, 0, stream>>>(h, ln2g + l * DDIM, ln2b + l * DDIM, zb);
    dim3 g1(FDIM / 128, BN / 128);    // (32, 64)
    k_gemm_mfma<true, false, false><<<g1, 256, 0, stream>>>(
        (const u16*)zb, (const u16*)wt1, b1 + l * FDIM, nullptr, ff1b, BN, DDIM, FDIM);
    dim3 g2(DDIM / 128, BN / 128);    // (8, 64)
    k_gemm_mfma<false, true, true><<<g2, 256, 0, stream>>>(
        (const u16*)ff1b, (const u16*)wt2, b2 + l * DDIM, h, h, BN, FDIM, DDIM);
  }

  k_mean1<<<256, 256, 0, stream>>>(h, meanp);
  k_mean2<<<16, 256, 0, stream>>>(meanp, (float*)d_out);
}

// Round 18
// 1805.506 us; speedup vs baseline: 1.0427x; 1.0090x over previous
//
#include <hip/hip_runtime.h>
#include <hip/hip_bf16.h>

typedef unsigned short u16;
typedef unsigned int u32;
typedef __attribute__((ext_vector_type(8))) short short8v;
typedef __attribute__((ext_vector_type(4))) float f32x4;

// Problem dims
#define BB    4
#define NN    2048
#define DDIM  1024
#define HH    16
#define DH    64
#define MM    256
#define FDIM  4096
#define LL    4
#define QLD   3072   // fused qkv row stride

static constexpr float DN_    = 0.35355339059327373f;  // 64^-0.25
static constexpr float RATIO_ = 0.0625f;               // 256^-0.5
static constexpr float KEPS_  = 1e-4f;

__device__ __forceinline__ short f2bs(float f) {
  __hip_bfloat16 h = __float2bfloat16(f);
  return *(short*)&h;
}
__device__ __forceinline__ float bs2f(short s) {
  return __uint_as_float(((unsigned)(u16)s) << 16);
}
// A&S 7.1.26 erf, abs err <= 1.5e-7 (<< bf16 ulp)
__device__ __forceinline__ float erf_fast(float x) {
  float ax = fabsf(x);
  float t = 1.f / (1.f + 0.3275911f * ax);
  float y = t * (0.254829592f + t * (-0.284496736f + t * (1.421413741f +
            t * (-1.453152027f + t * 1.061405429f))));
  float r = 1.f - y * __expf(-ax * ax);
  return copysignf(r, x);
}

// async global->LDS 16B: LDS dest wave-uniform base + lane*16
__device__ __forceinline__ void gload_lds16(const void* g, void* l) {
  __builtin_amdgcn_global_load_lds(
      (const __attribute__((address_space(1))) u32*)g,
      (__attribute__((address_space(3))) u32*)l, 16, 0, 0);
}

// counted-vmcnt pipeline primitives (T4; semantics proven correct in r14)
#define VMCNT4() asm volatile("s_waitcnt vmcnt(4)" ::: "memory")
#define VMCNT0() asm volatile("s_waitcnt vmcnt(0)" ::: "memory")
#define BAR() do { asm volatile("" ::: "memory"); __builtin_amdgcn_s_barrier(); \
                   asm volatile("" ::: "memory"); } while (0)

// ---------------------------------------------------------------- diagnostics
__global__ __launch_bounds__(256) void k_sentinel(float* __restrict__ out, float val) {
  int i = blockIdx.x * 256 + threadIdx.x;
  if (i < BB * DDIM) out[i] = val;
}

// ---------------------------------------------------------------- embed + LN1(layer0) fused
__global__ __launch_bounds__(256) void k_embed_ln(const int* __restrict__ x,
    const float* __restrict__ tok, const float* __restrict__ pos,
    const float* __restrict__ g, const float* __restrict__ b,
    float* __restrict__ h, __hip_bfloat16* __restrict__ zb) {
  int r = blockIdx.x, t = threadIdx.x;
  int n = r & (NN - 1);
  int id = x[r];
  const float* tr = tok + (size_t)id * DDIM;
  const float* pr = pos + (size_t)n * DDIM;
  float* hr = h + (size_t)r * DDIM;
  float v[4], s = 0.f, s2 = 0.f;
#pragma unroll
  for (int i = 0; i < 4; i++) {
    int d = t + i * 256;
    v[i] = tr[d] + pr[d];
    hr[d] = v[i];
    s += v[i]; s2 += v[i] * v[i];
  }
#pragma unroll
  for (int o = 32; o > 0; o >>= 1) { s += __shfl_down(s, o); s2 += __shfl_down(s2, o); }
  __shared__ float ws[8];
  int wid = t >> 6, lane = t & 63;
  if (lane == 0) { ws[wid] = s; ws[4 + wid] = s2; }
  __syncthreads();
  s = ws[0] + ws[1] + ws[2] + ws[3];
  s2 = ws[4] + ws[5] + ws[6] + ws[7];
  float mu = s * (1.f / DDIM);
  float var = s2 * (1.f / DDIM) - mu * mu;
  float rstd = rsqrtf(var + 1e-5f);
  __hip_bfloat16* orow = zb + (size_t)r * DDIM;
#pragma unroll
  for (int i = 0; i < 4; i++) {
    int d = t + i * 256;
    orow[d] = __float2bfloat16((v[i] - mu) * rstd * g[d] + b[d]);
  }
}

// ---------------------------------------------------------------- layernorm (bf16 out)
__global__ __launch_bounds__(256) void k_ln(const float* __restrict__ in,
    const float* __restrict__ g, const float* __restrict__ b,
    __hip_bfloat16* __restrict__ out) {
  int r = blockIdx.x, t = threadIdx.x;
  const float* xr = in + (size_t)r * DDIM;
  float v[4], s = 0.f, s2 = 0.f;
#pragma unroll
  for (int i = 0; i < 4; i++) {
    v[i] = xr[t + i * 256];
    s += v[i]; s2 += v[i] * v[i];
  }
#pragma unroll
  for (int o = 32; o > 0; o >>= 1) { s += __shfl_down(s, o); s2 += __shfl_down(s2, o); }
  __shared__ float ws[8];
  int wid = t >> 6, lane = t & 63;
  if (lane == 0) { ws[wid] = s; ws[4 + wid] = s2; }
  __syncthreads();
  s = ws[0] + ws[1] + ws[2] + ws[3];
  s2 = ws[4] + ws[5] + ws[6] + ws[7];
  float mu = s * (1.f / DDIM);
  float var = s2 * (1.f / DDIM) - mu * mu;
  float rstd = rsqrtf(var + 1e-5f);
  __hip_bfloat16* orow = out + (size_t)r * DDIM;
#pragma unroll
  for (int i = 0; i < 4; i++) {
    int d = t + i * 256;
    orow[d] = __float2bfloat16((v[i] - mu) * rstd * g[d] + b[d]);
  }
}

// ---------------------------------------------------------------- ALL weight transposes + bias concat, one dispatch
__global__ __launch_bounds__(256) void k_wtall(const float* __restrict__ Wq,
    const float* __restrict__ Wk, const float* __restrict__ Wv,
    const float* __restrict__ Wo, const float* __restrict__ W1,
    const float* __restrict__ W2, const float* __restrict__ bq,
    const float* __restrict__ bk, const float* __restrict__ bv,
    __hip_bfloat16* __restrict__ wt, float* __restrict__ bcat) {
  int id = blockIdx.x;
  int t = threadIdx.x;
  if (id >= 3072) {                     // bias concat: 12 blocks
    int i = (id - 3072) * 256 + t;
    bcat[i] = i < 1024 ? bq[i] : (i < 2048 ? bk[i - 1024] : bv[i - 2048]);
    return;
  }
  const float* W;
  __hip_bfloat16* Wt;
  int K, N, n0, k0;
  if (id < 1024) {                      // Wq|Wk|Wv|Wo: 256 tiles each
    int which = id >> 8, local = id & 255;
    W = which == 0 ? Wq : which == 1 ? Wk : which == 2 ? Wv : Wo;
    Wt = wt + (size_t)which * 1048576;
    K = 1024; N = 1024;
    n0 = (local & 15) * 64; k0 = (local >> 4) * 64;
  } else if (id < 2048) {               // W1: K=1024, N=4096
    int local = id - 1024;
    W = W1; Wt = wt + (size_t)4 * 1048576;
    K = 1024; N = 4096;
    n0 = (local & 63) * 64; k0 = (local >> 6) * 64;
  } else {                              // W2: K=4096, N=1024
    int local = id - 2048;
    W = W2; Wt = wt + (size_t)8 * 1048576;
    K = 4096; N = 1024;
    n0 = (local & 15) * 64; k0 = (local >> 4) * 64;
  }
  __shared__ float tl[64][68];
#pragma unroll
  for (int i = 0; i < 4; i++) {
    int kl = (t >> 4) + i * 16;
    float4 f = *(const float4*)&W[(size_t)(k0 + kl) * N + n0 + (t & 15) * 4];
    tl[kl][(t & 15) * 4 + 0] = f.x;
    tl[kl][(t & 15) * 4 + 1] = f.y;
    tl[kl][(t & 15) * 4 + 2] = f.z;
    tl[kl][(t & 15) * 4 + 3] = f.w;
  }
  __syncthreads();
  int nl = t >> 2;
#pragma unroll
  for (int i = 0; i < 4; i++) {
    int kl = (t & 3) * 4 + i * 16;
    size_t ob = (size_t)(n0 + nl) * K + k0 + kl;
    Wt[ob + 0] = __float2bfloat16(tl[kl + 0][nl]);
    Wt[ob + 1] = __float2bfloat16(tl[kl + 1][nl]);
    Wt[ob + 2] = __float2bfloat16(tl[kl + 2][nl]);
    Wt[ob + 3] = __float2bfloat16(tl[kl + 3][nl]);
  }
}

// ---------------------------------------------------------------- MFMA GEMM 128x128
// 3-buffer counted-vmcnt pipeline (48KB LDS keeps 3 blocks/CU; VGPR-limited
// anyway). STG(oldest) -> COMPUTE(cur) -> vmcnt(4) -> s_barrier.
template <bool GELU, bool RES, bool OUTF32>
__global__ __launch_bounds__(256) void k_gemm_mfma(
    const u16* __restrict__ A, const u16* __restrict__ Bt,
    const float* __restrict__ bias, const float* __restrict__ Cin,
    void* __restrict__ Cout, int M, int K, int Nc) {
  __shared__ short As[3][128 * 32];
  __shared__ short Bs[3][128 * 32];
  int t = threadIdx.x;
  int lane = t & 63, w = t >> 6;
  int wr = w >> 1, wc = w & 1;
  int nwg = gridDim.x * gridDim.y;
  int id = blockIdx.y * gridDim.x + blockIdx.x;
  int swz = (id & 7) * (nwg >> 3) + (id >> 3);
  int bx = swz % gridDim.x, by = swz / gridDim.x;
  int row0 = by * 128, col0 = bx * 128;
  f32x4 acc[4][4];
  f32x4 z4 = {0.f, 0.f, 0.f, 0.f};
#pragma unroll
  for (int i = 0; i < 4; i++)
#pragma unroll
    for (int j = 0; j < 4; j++) acc[i][j] = z4;
  int fr = lane & 15;
  int fc = lane >> 4;
  int offA[4], offB[4];
#pragma unroll
  for (int f = 0; f < 4; f++) {
    int ra = wr * 64 + f * 16 + fr;
    offA[f] = ra * 32 + (fc ^ ((ra >> 1) & 3)) * 8;
    int rb = wc * 64 + f * 16 + fr;
    offB[f] = rb * 32 + (fc ^ ((rb >> 1) & 3)) * 8;
  }
  int c0 = t, c1 = 256 + t;
  int r0 = c0 >> 2, cl0 = (c0 & 3) ^ ((r0 >> 1) & 3);
  int r1 = c1 >> 2, cl1 = (c1 & 3) ^ ((r1 >> 1) & 3);
  const u16* pA0 = A + (size_t)(row0 + r0) * K + cl0 * 8;
  const u16* pA1 = A + (size_t)(row0 + r1) * K + cl1 * 8;
  const u16* pB0 = Bt + (size_t)(col0 + r0) * K + cl0 * 8;
  const u16* pB1 = Bt + (size_t)(col0 + r1) * K + cl1 * 8;

  auto STG = [&](short* Ab, short* Bb) {
    gload_lds16(pA0, Ab + c0 * 8);
    gload_lds16(pA1, Ab + c1 * 8);
    gload_lds16(pB0, Bb + c0 * 8);
    gload_lds16(pB1, Bb + c1 * 8);
    pA0 += 32; pA1 += 32; pB0 += 32; pB1 += 32;
  };
  auto COMPUTE = [&](const short* Ab, const short* Bb) {
    short8v af[4], bfr[4];
#pragma unroll
    for (int f = 0; f < 4; f++) {
      af[f] = *(const short8v*)(Ab + offA[f]);
      bfr[f] = *(const short8v*)(Bb + offB[f]);
    }
#pragma unroll
    for (int fi = 0; fi < 4; fi++)
#pragma unroll
      for (int fj = 0; fj < 4; fj++)
        acc[fi][fj] = __builtin_amdgcn_mfma_f32_16x16x32_bf16(
            af[fi], bfr[fj], acc[fi][fj], 0, 0, 0);
  };

  int KT = K >> 5;            // >= 3 at all call sites (32, 128)
  short *A0 = As[0], *A1 = As[1], *A2 = As[2];
  short *B0 = Bs[0], *B1 = Bs[1], *B2 = Bs[2];
  STG(A0, B0);                // k-step 0
  STG(A1, B1);                // k-step 1
  VMCNT4(); BAR();            // step 0 resident
  for (int kt = 0; kt < KT - 2; ++kt) {
    STG(A2, B2);              // k-step kt+2 into oldest buffer (read at kt-1)
    COMPUTE(A0, B0);          // k-step kt
    VMCNT4(); BAR();          // k-step kt+1 resident
    short* ta = A0; A0 = A1; A1 = A2; A2 = ta;
    short* tb = B0; B0 = B1; B1 = B2; B2 = tb;
  }
  COMPUTE(A0, B0);            // k-step KT-2 (resident from last loop vmcnt)
  VMCNT0(); BAR();
  COMPUTE(A1, B1);            // k-step KT-1
#pragma unroll
  for (int fi = 0; fi < 4; fi++) {
#pragma unroll
    for (int fj = 0; fj < 4; fj++) {
#pragma unroll
      for (int ri = 0; ri < 4; ri++) {
        int row = row0 + wr * 64 + fi * 16 + (lane >> 4) * 4 + ri;
        int col = col0 + wc * 64 + fj * 16 + fr;
        float vv = acc[fi][fj][ri] + bias[col];
        if (GELU) vv = 0.5f * vv * (1.f + erf_fast(vv * 0.70710678118f));
        if (RES) vv += Cin[(size_t)row * Nc + col];
        if (OUTF32) ((float*)Cout)[(size_t)row * Nc + col] = vv;
        else ((__hip_bfloat16*)Cout)[(size_t)row * Nc + col] = __float2bfloat16(vv);
      }
    }
  }
}

// ---------------------------------------------------------------- fused key-side, MFMA, online-max, m-split
__global__ __launch_bounds__(256) void k_kv(const u16* __restrict__ kq,
    const u16* __restrict__ vq, const float* __restrict__ P,
    float* __restrict__ es, float* __restrict__ mxc, float* __restrict__ svc,
    float* __restrict__ ctx_part) {
  int bh = blockIdx.x >> 3;
  int chunk = (blockIdx.x >> 1) & 3;
  int mh = blockIdx.x & 1;
  int b = bh >> 4, hh = bh & 15;
  int t = threadIdx.x, lane = t & 63, w = t >> 6;
  int fr = lane & 15, kc = lane >> 4;
  __shared__ short Pl[128 * 64];
  __shared__ short ksl[32 * 64];
  __shared__ short vtl[64 * 32];
  __shared__ short kpl[128 * 32];
  __shared__ float dgs[32];
  __shared__ float wredk[4];
  __shared__ float svl[32][64];
#pragma unroll
  for (int i = 0; i < 4; i++) {
    int e = i * 256 + t;
    int m = e >> 3, j = e & 7;
    const float* src = P + (size_t)(mh * 128 + m) * 64 + j * 8;
    float4 f0 = *(const float4*)src;
    float4 f1 = *(const float4*)(src + 4);
    short* dst = Pl + m * 64 + ((j ^ (m & 7)) << 3);
    dst[0] = f2bs(f0.x); dst[1] = f2bs(f0.y); dst[2] = f2bs(f0.z); dst[3] = f2bs(f0.w);
    dst[4] = f2bs(f1.x); dst[5] = f2bs(f1.y); dst[6] = f2bs(f1.z); dst[7] = f2bs(f1.w);
  }
  f32x4 z4 = {0.f, 0.f, 0.f, 0.f};
  f32x4 accc[2][4];
#pragma unroll
  for (int i = 0; i < 2; i++)
#pragma unroll
    for (int j = 0; j < 4; j++) accc[i][j] = z4;
  float ksp[2] = {0.f, 0.f};
  float svp[8] = {0.f, 0.f, 0.f, 0.f, 0.f, 0.f, 0.f, 0.f};
  float m_run = -3e38f;
  int r8 = t >> 3, j8 = t & 7;
  for (int tile = 0; tile < 16; ++tile) {
    int n0 = chunk * 512 + tile * 32;
    __syncthreads();
    {
      size_t gk = ((size_t)(b * NN) + n0 + r8) * QLD + hh * 64 + j8 * 8;
      short8v k8 = *(const short8v*)(kq + gk);
      *(short8v*)(ksl + r8 * 64 + ((j8 ^ (r8 & 7)) << 3)) = k8;
      float s2 = 0.f;
#pragma unroll
      for (int ii = 0; ii < 8; ii++) { float rv = bs2f(k8[ii]); s2 += rv * rv; }
      s2 += __shfl_down(s2, 4); s2 += __shfl_down(s2, 2); s2 += __shfl_down(s2, 1);
      if (j8 == 0) dgs[r8] = 0.0625f * s2;
      short8v v8 = *(const short8v*)(vq + gk);
#pragma unroll
      for (int ii = 0; ii < 8; ii++) {
        int d = j8 * 8 + ii;
        vtl[d * 32 + (((r8 >> 3) ^ ((d >> 1) & 3)) << 3) + (r8 & 7)] = v8[ii];
        svp[ii] += bs2f(v8[ii]);
      }
    }
    __syncthreads();
    f32x4 accd[2][2];
#pragma unroll
    for (int nt = 0; nt < 2; nt++)
#pragma unroll
      for (int mt = 0; mt < 2; mt++) accd[nt][mt] = z4;
#pragma unroll
    for (int s = 0; s < 2; s++) {
      short8v afr[2];
#pragma unroll
      for (int nt = 0; nt < 2; nt++) {
        int rr = nt * 16 + fr;
        afr[nt] = *(const short8v*)(ksl + rr * 64 + (((s * 4 + kc) ^ (rr & 7)) << 3));
      }
#pragma unroll
      for (int mt = 0; mt < 2; mt++) {
        int ml = w * 32 + mt * 16 + fr;
        short8v bfp = *(const short8v*)(Pl + ml * 64 + (((s * 4 + kc) ^ (ml & 7)) << 3));
#pragma unroll
        for (int nt = 0; nt < 2; nt++)
          accd[nt][mt] = __builtin_amdgcn_mfma_f32_16x16x32_bf16(afr[nt], bfp, accd[nt][mt], 0, 0, 0);
      }
    }
    float tm = -3e38f;
#pragma unroll
    for (int nt = 0; nt < 2; nt++)
#pragma unroll
      for (int mt = 0; mt < 2; mt++) {
        accd[nt][mt] = accd[nt][mt] * DN_;
        tm = fmaxf(tm, fmaxf(fmaxf(accd[nt][mt][0], accd[nt][mt][1]),
                             fmaxf(accd[nt][mt][2], accd[nt][mt][3])));
      }
#pragma unroll
    for (int o = 32; o > 0; o >>= 1) tm = fmaxf(tm, __shfl_xor(tm, o));
    if (lane == 0) wredk[w] = tm;
    __syncthreads();
    float bm = fmaxf(fmaxf(wredk[0], wredk[1]), fmaxf(wredk[2], wredk[3]));
    float nm = fmaxf(m_run, bm);
    float fac = __expf(m_run - nm);
#pragma unroll
    for (int mt = 0; mt < 2; mt++) {
      ksp[mt] *= fac;
#pragma unroll
      for (int dt = 0; dt < 4; dt++) accc[mt][dt] = accc[mt][dt] * fac;
    }
    m_run = nm;
#pragma unroll
    for (int nt = 0; nt < 2; nt++)
#pragma unroll
      for (int mt = 0; mt < 2; mt++)
#pragma unroll
        for (int ri = 0; ri < 4; ri++) {
          int n = nt * 16 + kc * 4 + ri;
          int ml = w * 32 + mt * 16 + fr;
          float kpv = __expf(accd[nt][mt][ri] - dgs[n] - m_run);
          ksp[mt] += kpv;
          kpl[ml * 32 + (((n >> 3) ^ ((ml >> 1) & 3)) << 3) + (n & 7)] = f2bs(kpv);
        }
    short8v bvv[4];
#pragma unroll
    for (int dt = 0; dt < 4; dt++) {
      int d = dt * 16 + fr;
      bvv[dt] = *(const short8v*)(vtl + d * 32 + ((kc ^ ((d >> 1) & 3)) << 3));
    }
#pragma unroll
    for (int mt = 0; mt < 2; mt++) {
      int ml = w * 32 + mt * 16 + fr;
      short8v ak = *(const short8v*)(kpl + ml * 32 + ((kc ^ ((ml >> 1) & 3)) << 3));
#pragma unroll
      for (int dt = 0; dt < 4; dt++)
        accc[mt][dt] = __builtin_amdgcn_mfma_f32_16x16x32_bf16(ak, bvv[dt], accc[mt][dt], 0, 0, 0);
    }
  }
#pragma unroll
  for (int mt = 0; mt < 2; mt++) {
    float vv = ksp[mt];
    vv += __shfl_xor(vv, 16);
    vv += __shfl_xor(vv, 32);
    if (lane < 16)
      es[((size_t)bh * 4 + chunk) * MM + mh * 128 + w * 32 + mt * 16 + lane] = vv;
  }
  if (t == 0) mxc[((size_t)bh * 4 + chunk) * 2 + mh] = m_run;
#pragma unroll
  for (int ii = 0; ii < 8; ii++) svl[r8][j8 * 8 + ii] = svp[ii];
  __syncthreads();
  if (mh == 0 && t < 64) {
    float s = 0.f;
#pragma unroll
    for (int r = 0; r < 32; r++) s += svl[r][t];
    svc[((size_t)bh * 4 + chunk) * 64 + t] = s;
  }
  size_t base = ((size_t)(chunk * 64 + bh)) * MM * DH;
#pragma unroll
  for (int mt = 0; mt < 2; mt++)
#pragma unroll
    for (int dt = 0; dt < 4; dt++)
#pragma unroll
      for (int ri = 0; ri < 4; ri++) {
        int mg = mh * 128 + w * 32 + mt * 16 + kc * 4 + ri;
        int d = dt * 16 + fr;
        ctx_part[base + mg * 64 + d] = accc[mt][dt][ri];
      }
}

// ---------------------------------------------------------------- combine 4chunks x 2mhalves
__global__ __launch_bounds__(256) void k_ctxred(const float* __restrict__ part,
    const float* __restrict__ es, const float* __restrict__ mxc,
    const float* __restrict__ svc, float* __restrict__ ksum,
    u16* __restrict__ ctxT) {
  int bh = blockIdx.x, t = threadIdx.x;
  __shared__ float tl[64][65];
  __shared__ float facs[8];
  __shared__ float svg[64];
  float mg = -3e38f;
#pragma unroll
  for (int i = 0; i < 8; i++) mg = fmaxf(mg, mxc[(size_t)bh * 8 + i]);
  if (t < 8) facs[t] = __expf(mxc[(size_t)bh * 8 + t] - mg);
  if (t >= 64 && t < 128) {
    int d = t - 64;
    svg[d] = svc[((size_t)bh * 4 + 0) * 64 + d] + svc[((size_t)bh * 4 + 1) * 64 + d] +
             svc[((size_t)bh * 4 + 2) * 64 + d] + svc[((size_t)bh * 4 + 3) * 64 + d];
  }
  __syncthreads();
  {
    size_t eb = (size_t)bh * 4 * MM;
    int mhb = t >> 7;
    float s = es[eb + t] * facs[0 * 2 + mhb] + es[eb + MM + t] * facs[1 * 2 + mhb] +
              es[eb + 2 * MM + t] * facs[2 * 2 + mhb] + es[eb + 3 * MM + t] * facs[3 * 2 + mhb];
    ksum[bh * MM + t] = RATIO_ * (s + KEPS_ * 2048.0f);
  }
  const size_t CH = (size_t)64 * MM * DH;
  for (int mt = 0; mt < 4; mt++) {
    int mhb = mt >> 1;
    float f0 = facs[0 * 2 + mhb], f1 = facs[1 * 2 + mhb];
    float f2 = facs[2 * 2 + mhb], f3 = facs[3 * 2 + mhb];
    __syncthreads();
#pragma unroll
    for (int i = 0; i < 16; i++) {
      int e = i * 256 + t;
      int ml = e >> 6, d = e & 63;
      size_t off = (size_t)bh * MM * DH + (size_t)(mt * 64 + ml) * 64 + d;
      float ev = part[off] * f0 + part[CH + off] * f1 +
                 part[2 * CH + off] * f2 + part[3 * CH + off] * f3;
      tl[ml][d] = RATIO_ * (ev + KEPS_ * svg[d]);
    }
    __syncthreads();
#pragma unroll
    for (int i = 0; i < 16; i++) {
      int e = i * 256 + t;
      int d = e >> 6, ml = e & 63;
      ctxT[((size_t)bh * 64 + d) * 256 + mt * 64 + ml] = (u16)f2bs(tl[ml][d]);
    }
  }
}

// ---------------------------------------------------------------- fused query-side, MFMA
__global__ __launch_bounds__(256) void k_attn_fused(const u16* __restrict__ q,
    const float* __restrict__ P, const float* __restrict__ ksum,
    const u16* __restrict__ ctxT, __hip_bfloat16* __restrict__ attn) {
  int bh = blockIdx.x >> 5, rb = blockIdx.x & 31;
  int b = bh >> 4, hh = bh & 15;
  int n0 = rb * 64;
  int t = threadIdx.x, lane = t & 63, w = t >> 6;
  int fr = lane & 15, kc = lane >> 4;
  __shared__ short qsl[64 * 64];
  __shared__ short qpl[64 * 256];
  __shared__ short ctl[64 * 256];
  __shared__ float dgs[64];
  __shared__ float ks_l[MM];
  __shared__ float wred[4][64];
  __shared__ float mx_l[64];
  __shared__ float inv_l[64];
  short8v pf[4][2];
#pragma unroll
  for (int mt = 0; mt < 4; mt++)
#pragma unroll
    for (int s = 0; s < 2; s++) {
      int m = w * 64 + mt * 16 + fr;
      const float* src = P + m * 64 + s * 32 + kc * 8;
      float4 f0 = *(const float4*)src;
      float4 f1 = *(const float4*)(src + 4);
      short8v pv;
      pv[0] = f2bs(f0.x); pv[1] = f2bs(f0.y); pv[2] = f2bs(f0.z); pv[3] = f2bs(f0.w);
      pv[4] = f2bs(f1.x); pv[5] = f2bs(f1.y); pv[6] = f2bs(f1.z); pv[7] = f2bs(f1.w);
      pf[mt][s] = pv;
    }
  ks_l[t] = ksum[bh * MM + t];
  {
    int rr = t >> 2, j4 = t & 3;
    size_t gq = ((size_t)(b * NN) + n0 + rr) * QLD + hh * 64 + j4 * 16;
    short8v q0 = *(const short8v*)(q + gq);
    short8v q1 = *(const short8v*)(q + gq + 8);
    *(short8v*)(qsl + rr * 64 + (((2 * j4) ^ (rr & 7)) << 3)) = q0;
    *(short8v*)(qsl + rr * 64 + (((2 * j4 + 1) ^ (rr & 7)) << 3)) = q1;
    float s2 = 0.f;
#pragma unroll
    for (int ii = 0; ii < 8; ii++) {
      float a = bs2f(q0[ii]), c = bs2f(q1[ii]);
      s2 += a * a + c * c;
    }
    s2 += __shfl_down(s2, 2); s2 += __shfl_down(s2, 1);
    if (j4 == 0) dgs[rr] = 0.0625f * s2;
  }
#pragma unroll
  for (int i = 0; i < 8; i++) {
    int e = i * 256 + t;
    int d = e >> 5, c = e & 31;
    short8v cv = *(const short8v*)(ctxT + ((size_t)bh * 64 + d) * 256 + c * 8);
    *(short8v*)(ctl + d * 256 + ((c ^ (d & 7)) << 3)) = cv;
  }
  __syncthreads();
  f32x4 z4 = {0.f, 0.f, 0.f, 0.f};
  f32x4 accd[4][4];
#pragma unroll
  for (int i = 0; i < 4; i++)
#pragma unroll
    for (int j = 0; j < 4; j++) accd[i][j] = z4;
#pragma unroll
  for (int s = 0; s < 2; s++) {
    short8v afr[4];
#pragma unroll
    for (int nt = 0; nt < 4; nt++) {
      int rr = nt * 16 + fr;
      afr[nt] = *(const short8v*)(qsl + rr * 64 + (((s * 4 + kc) ^ (rr & 7)) << 3));
    }
#pragma unroll
    for (int mt = 0; mt < 4; mt++)
#pragma unroll
      for (int nt = 0; nt < 4; nt++)
        accd[nt][mt] = __builtin_amdgcn_mfma_f32_16x16x32_bf16(afr[nt], pf[mt][s], accd[nt][mt], 0, 0, 0);
  }
#pragma unroll
  for (int i = 0; i < 4; i++)
#pragma unroll
    for (int j = 0; j < 4; j++) accd[i][j] = accd[i][j] * DN_;
  {
    float pmx[16];
#pragma unroll
    for (int nt = 0; nt < 4; nt++)
#pragma unroll
      for (int ri = 0; ri < 4; ri++) {
        float m_ = fmaxf(fmaxf(accd[nt][0][ri], accd[nt][1][ri]),
                         fmaxf(accd[nt][2][ri], accd[nt][3][ri]));
#pragma unroll
        for (int o = 1; o < 16; o <<= 1) m_ = fmaxf(m_, __shfl_xor(m_, o));
        pmx[nt * 4 + ri] = m_;
      }
    if (fr == 0) {
#pragma unroll
      for (int nt = 0; nt < 4; nt++)
#pragma unroll
        for (int ri = 0; ri < 4; ri++)
          wred[w][nt * 16 + kc * 4 + ri] = pmx[nt * 4 + ri];
    }
  }
  __syncthreads();
  if (t < 64)
    mx_l[t] = fmaxf(fmaxf(wred[0][t], wred[1][t]), fmaxf(wred[2][t], wred[3][t]));
  __syncthreads();
  {
    float sp[16];
#pragma unroll
    for (int i = 0; i < 16; i++) sp[i] = 0.f;
#pragma unroll
    for (int nt = 0; nt < 4; nt++)
#pragma unroll
      for (int mt = 0; mt < 4; mt++)
#pragma unroll
        for (int ri = 0; ri < 4; ri++) {
          int n = nt * 16 + kc * 4 + ri;
          int m = w * 64 + mt * 16 + fr;
          float kpv = RATIO_ * (__expf(accd[nt][mt][ri] - dgs[n] - mx_l[n]) + KEPS_);
          sp[nt * 4 + ri] += kpv * ks_l[m];
          int c = m >> 3;
          qpl[n * 256 + ((c ^ (n & 7)) << 3) + (m & 7)] = f2bs(kpv);
        }
#pragma unroll
    for (int i = 0; i < 16; i++) {
#pragma unroll
      for (int o = 1; o < 16; o <<= 1) sp[i] += __shfl_xor(sp[i], o);
    }
    if (fr == 0) {
#pragma unroll
      for (int nt = 0; nt < 4; nt++)
#pragma unroll
        for (int ri = 0; ri < 4; ri++)
          wred[w][nt * 16 + kc * 4 + ri] = sp[nt * 4 + ri];
    }
  }
  __syncthreads();
  if (t < 64)
    inv_l[t] = 1.f / (wred[0][t] + wred[1][t] + wred[2][t] + wred[3][t]);
  __syncthreads();
  f32x4 acc2[4];
#pragma unroll
  for (int dt = 0; dt < 4; dt++) acc2[dt] = z4;
  int nrow = w * 16 + fr;
#pragma unroll
  for (int ks = 0; ks < 8; ks++) {
    int c = ks * 4 + kc;
    short8v aq = *(const short8v*)(qpl + nrow * 256 + ((c ^ (nrow & 7)) << 3));
#pragma unroll
    for (int dt = 0; dt < 4; dt++) {
      int d = dt * 16 + fr;
      short8v bc = *(const short8v*)(ctl + d * 256 + ((c ^ (d & 7)) << 3));
      acc2[dt] = __builtin_amdgcn_mfma_f32_16x16x32_bf16(aq, bc, acc2[dt], 0, 0, 0);
    }
  }
#pragma unroll
  for (int dt = 0; dt < 4; dt++)
#pragma unroll
    for (int ri = 0; ri < 4; ri++) {
      int n = w * 16 + kc * 4 + ri;
      int d = dt * 16 + fr;
      attn[((size_t)(b * NN) + n0 + n) * DDIM + hh * 64 + d] =
          __float2bfloat16(acc2[dt][ri] * inv_l[n]);
    }
}

// ---------------------------------------------------------------- mean over N, two-stage
__global__ __launch_bounds__(256) void k_mean1(const float* __restrict__ h,
                                               float* __restrict__ part) {
  int c = blockIdx.x >> 2, b = blockIdx.x & 3;
  int t = threadIdx.x;
  float s0 = 0.f, s1 = 0.f, s2 = 0.f, s3 = 0.f;
  for (int n = c * 32; n < c * 32 + 32; n++) {
    float4 f = *(const float4*)&h[((size_t)b * NN + n) * DDIM + t * 4];
    s0 += f.x; s1 += f.y; s2 += f.z; s3 += f.w;
  }
  float* p = part + (size_t)c * (BB * DDIM) + b * DDIM + t * 4;
  p[0] = s0; p[1] = s1; p[2] = s2; p[3] = s3;
}
__global__ __launch_bounds__(256) void k_mean2(const float* __restrict__ part,
                                               float* __restrict__ out) {
  int idx = blockIdx.x * 256 + threadIdx.x;
  float s = 0.f;
  for (int c = 0; c < 64; c++) s += part[(size_t)c * (BB * DDIM) + idx];
  out[idx] = s * (1.f / NN);
}

// ================================================================ host
extern "C" void kernel_launch(void* const* d_in, const int* in_sizes, int n_in,
                              void* d_out, int out_size, void* d_ws, size_t ws_size,
                              hipStream_t stream) {
  static const long long EXP[21] = {
      8192, 8192, 32768000, 2097152, 4096, 4096,
      4194304, 4096, 4194304, 4096, 4194304, 4096, 4194304, 4096,
      65536, 4096, 4096, 16777216, 16384, 16777216, 4096
  };
  const size_t NEED_WS = 197559552;  // bytes (<= 205.6MB proven in round 5)
  float sentinel = 0.f;
  if (n_in != 21) {
    sentinel = 100000.f + 100.f * (float)n_in;
  } else {
    for (int i = 0; i < 21; i++)
      if ((long long)in_sizes[i] != EXP[i]) { sentinel = 1000.f + 100.f * i; break; }
  }
  if (sentinel == 0.f && out_size != BB * DDIM) sentinel = 6000.f;
  if (sentinel == 0.f && ws_size < NEED_WS) {
    float units = (float)(ws_size / (32ull << 20));
    if (units > 40.f) units = 40.f;
    sentinel = 5000.f + 100.f * units;
  }
  if (sentinel != 0.f) {
    k_sentinel<<<16, 256, 0, stream>>>((float*)d_out, sentinel);
    return;
  }

  const int* x = (const int*)d_in[0];
  const float* tok  = (const float*)d_in[2];
  const float* pos  = (const float*)d_in[3];
  const float* ln1g = (const float*)d_in[4];
  const float* ln1b = (const float*)d_in[5];
  const float* wq   = (const float*)d_in[6];
  const float* bq   = (const float*)d_in[7];
  const float* wk   = (const float*)d_in[8];
  const float* bk   = (const float*)d_in[9];
  const float* wv   = (const float*)d_in[10];
  const float* bv   = (const float*)d_in[11];
  const float* wo   = (const float*)d_in[12];
  const float* bo   = (const float*)d_in[13];
  const float* proj = (const float*)d_in[14];
  const float* ln2g = (const float*)d_in[15];
  const float* ln2b = (const float*)d_in[16];
  const float* w1   = (const float*)d_in[17];
  const float* b1   = (const float*)d_in[18];
  const float* w2   = (const float*)d_in[19];
  const float* b2   = (const float*)d_in[20];

  const int BN = BB * NN;                    // 8192
  const size_t SZ = (size_t)BN * DDIM;       // 8,388,608 floats
  const size_t MEG = 1048576;
  float* ws    = (float*)d_ws;
  float* h     = ws;                          // SZ f32
  u16* qkvb    = (u16*)(ws + SZ);             // [8192][3072] bf16
  __hip_bfloat16* zb   = (__hip_bfloat16*)(ws + 4 * SZ);       // SZ bf16
  float* ctx   = ws + 4 * SZ + SZ / 2;        // ctxT bf16 region
  float* ksum  = ctx + (size_t)BB * HH * MM * DH;
  float* bmaxp = ksum + BB * HH * MM;
  float* bcat  = bmaxp + 4096;                // 3072 f32
  float* mxp   = bmaxp + BB * HH * 128;
  __hip_bfloat16* wt = (__hip_bfloat16*)(mxp + 64);            // 12M bf16
  float* ctxp  = (float*)(wt + 12 * MEG);     // 4 x 1,048,576 f32 partials
  float* esb   = ctxp + 4 * MEG;              // 64*4*256
  float* mxcb  = esb + 65536;                 // 512 (bh x chunk x mh)
  float* svcb  = mxcb + 512;                  // 64*4*64
  u16* ctxT    = (u16*)ctx;
  __hip_bfloat16* ff1b = (__hip_bfloat16*)qkvb;   // overlay (qkv dead during FFN)
  __hip_bfloat16* zab  = (__hip_bfloat16*)ctxp;   // overlay (ctxp dead after ctxred)
  float* meanp = ctxp;

  k_embed_ln<<<BN, 256, 0, stream>>>(x, tok, pos, ln1g, ln1b, h, zb);

  for (int l = 0; l < LL; l++) {
    const float* Wq = wq + (size_t)l * DDIM * DDIM;
    const float* Wk = wk + (size_t)l * DDIM * DDIM;
    const float* Wv = wv + (size_t)l * DDIM * DDIM;
    const float* Wo = wo + (size_t)l * DDIM * DDIM;
    const float* W1 = w1 + (size_t)l * DDIM * FDIM;
    const float* W2 = w2 + (size_t)l * FDIM * DDIM;
    const float* Pl = proj + (size_t)l * MM * DH;
    __hip_bfloat16* wtq = wt;             // [3072][1024] concatenated q|k|v
    __hip_bfloat16* wto = wt + 3 * MEG;
    __hip_bfloat16* wt1 = wt + 4 * MEG;
    __hip_bfloat16* wt2 = wt + 8 * MEG;

    k_wtall<<<3084, 256, 0, stream>>>(Wq, Wk, Wv, Wo, W1, W2,
                                      bq + l * DDIM, bk + l * DDIM, bv + l * DDIM,
                                      wt, bcat);

    if (l > 0)
      k_ln<<<BN, 256, 0, stream>>>(h, ln1g + l * DDIM, ln1b + l * DDIM, zb);

    dim3 gQKV(QLD / 128, BN / 128);   // (24, 64)
    k_gemm_mfma<false, false, false><<<gQKV, 256, 0, stream>>>(
        (const u16*)zb, (const u16*)wtq, bcat, nullptr, qkvb, BN, DDIM, QLD);

    k_kv<<<BB * HH * 8, 256, 0, stream>>>(qkvb + 1024, qkvb + 2048, Pl,
                                          esb, mxcb, svcb, ctxp);
    k_ctxred<<<BB * HH, 256, 0, stream>>>(ctxp, esb, mxcb, svcb, ksum, ctxT);
    k_attn_fused<<<BB * HH * 32, 256, 0, stream>>>(qkvb, Pl, ksum, ctxT, zab);

    dim3 gO(DDIM / 128, BN / 128);    // (8, 64)
    k_gemm_mfma<false, true, true><<<gO, 256, 0, stream>>>(
        (const u16*)zab, (const u16*)wto, bo + l * DDIM, h, h, BN, DDIM, DDIM);

    k_ln<<<BN, 256, 0, stream>>>(h, ln2g + l * DDIM, ln2b + l * DDIM, zb);
    dim3 g1(FDIM / 128, BN / 128);    // (32, 64)
    k_gemm_mfma<true, false, false><<<g1, 256, 0, stream>>>(
        (const u16*)zb, (const u16*)wt1, b1 + l * FDIM, nullptr, ff1b, BN, DDIM, FDIM);
    dim3 g2(DDIM / 128, BN / 128);    // (8, 64)
    k_gemm_mfma<false, true, true><<<g2, 256, 0, stream>>>(
        (const u16*)ff1b, (const u16*)wt2, b2 + l * DDIM, h, h, BN, FDIM, DDIM);
  }

  k_mean1<<<256, 256, 0, stream>>>(h, meanp);
  k_mean2<<<16, 256, 0, stream>>>(meanp, (float*)d_out);
}

// Round 19
// 1714.720 us; speedup vs baseline: 1.0979x; 1.0529x over previous
//
#include <hip/hip_runtime.h>
#include <hip/hip_bf16.h>

typedef unsigned short u16;
typedef unsigned int u32;
typedef __attribute__((ext_vector_type(8))) short short8v;
typedef __attribute__((ext_vector_type(4))) float f32x4;

// Problem dims
#define BB    4
#define NN    2048
#define DDIM  1024
#define HH    16
#define DH    64
#define MM    256
#define FDIM  4096
#define LL    4
#define QLD   3072   // fused qkv row stride

static constexpr float DN_    = 0.35355339059327373f;  // 64^-0.25
static constexpr float RATIO_ = 0.0625f;               // 256^-0.5
static constexpr float KEPS_  = 1e-4f;

__device__ __forceinline__ short f2bs(float f) {
  __hip_bfloat16 h = __float2bfloat16(f);
  return *(short*)&h;
}
__device__ __forceinline__ float bs2f(short s) {
  return __uint_as_float(((unsigned)(u16)s) << 16);
}
// A&S 7.1.26 erf, abs err <= 1.5e-7 (<< bf16 ulp)
__device__ __forceinline__ float erf_fast(float x) {
  float ax = fabsf(x);
  float t = 1.f / (1.f + 0.3275911f * ax);
  float y = t * (0.254829592f + t * (-0.284496736f + t * (1.421413741f +
            t * (-1.453152027f + t * 1.061405429f))));
  float r = 1.f - y * __expf(-ax * ax);
  return copysignf(r, x);
}

// async global->LDS 16B: LDS dest wave-uniform base + lane*16
__device__ __forceinline__ void gload_lds16(const void* g, void* l) {
  __builtin_amdgcn_global_load_lds(
      (const __attribute__((address_space(1))) u32*)g,
      (__attribute__((address_space(3))) u32*)l, 16, 0, 0);
}

// counted-vmcnt pipeline primitives (T4; semantics proven correct r14/r18)
#define VMCNT4() asm volatile("s_waitcnt vmcnt(4)" ::: "memory")
#define VMCNT0() asm volatile("s_waitcnt vmcnt(0)" ::: "memory")
#define BAR() do { asm volatile("" ::: "memory"); __builtin_amdgcn_s_barrier(); \
                   asm volatile("" ::: "memory"); } while (0)

// ---------------------------------------------------------------- diagnostics
__global__ __launch_bounds__(256) void k_sentinel(float* __restrict__ out, float val) {
  int i = blockIdx.x * 256 + threadIdx.x;
  if (i < BB * DDIM) out[i] = val;
}

// ---------------------------------------------------------------- embed + LN1(layer0) fused
__global__ __launch_bounds__(256) void k_embed_ln(const int* __restrict__ x,
    const float* __restrict__ tok, const float* __restrict__ pos,
    const float* __restrict__ g, const float* __restrict__ b,
    float* __restrict__ h, __hip_bfloat16* __restrict__ zb) {
  int r = blockIdx.x, t = threadIdx.x;
  int n = r & (NN - 1);
  int id = x[r];
  const float* tr = tok + (size_t)id * DDIM;
  const float* pr = pos + (size_t)n * DDIM;
  float* hr = h + (size_t)r * DDIM;
  float v[4], s = 0.f, s2 = 0.f;
#pragma unroll
  for (int i = 0; i < 4; i++) {
    int d = t + i * 256;
    v[i] = tr[d] + pr[d];
    hr[d] = v[i];
    s += v[i]; s2 += v[i] * v[i];
  }
#pragma unroll
  for (int o = 32; o > 0; o >>= 1) { s += __shfl_down(s, o); s2 += __shfl_down(s2, o); }
  __shared__ float ws[8];
  int wid = t >> 6, lane = t & 63;
  if (lane == 0) { ws[wid] = s; ws[4 + wid] = s2; }
  __syncthreads();
  s = ws[0] + ws[1] + ws[2] + ws[3];
  s2 = ws[4] + ws[5] + ws[6] + ws[7];
  float mu = s * (1.f / DDIM);
  float var = s2 * (1.f / DDIM) - mu * mu;
  float rstd = rsqrtf(var + 1e-5f);
  __hip_bfloat16* orow = zb + (size_t)r * DDIM;
#pragma unroll
  for (int i = 0; i < 4; i++) {
    int d = t + i * 256;
    orow[d] = __float2bfloat16((v[i] - mu) * rstd * g[d] + b[d]);
  }
}

// ---------------------------------------------------------------- layernorm (bf16 out)
__global__ __launch_bounds__(256) void k_ln(const float* __restrict__ in,
    const float* __restrict__ g, const float* __restrict__ b,
    __hip_bfloat16* __restrict__ out) {
  int r = blockIdx.x, t = threadIdx.x;
  const float* xr = in + (size_t)r * DDIM;
  float v[4], s = 0.f, s2 = 0.f;
#pragma unroll
  for (int i = 0; i < 4; i++) {
    v[i] = xr[t + i * 256];
    s += v[i]; s2 += v[i] * v[i];
  }
#pragma unroll
  for (int o = 32; o > 0; o >>= 1) { s += __shfl_down(s, o); s2 += __shfl_down(s2, o); }
  __shared__ float ws[8];
  int wid = t >> 6, lane = t & 63;
  if (lane == 0) { ws[wid] = s; ws[4 + wid] = s2; }
  __syncthreads();
  s = ws[0] + ws[1] + ws[2] + ws[3];
  s2 = ws[4] + ws[5] + ws[6] + ws[7];
  float mu = s * (1.f / DDIM);
  float var = s2 * (1.f / DDIM) - mu * mu;
  float rstd = rsqrtf(var + 1e-5f);
  __hip_bfloat16* orow = out + (size_t)r * DDIM;
#pragma unroll
  for (int i = 0; i < 4; i++) {
    int d = t + i * 256;
    orow[d] = __float2bfloat16((v[i] - mu) * rstd * g[d] + b[d]);
  }
}

// ---------------------------------------------------------------- ALL weight transposes + bias concat, one dispatch
__global__ __launch_bounds__(256) void k_wtall(const float* __restrict__ Wq,
    const float* __restrict__ Wk, const float* __restrict__ Wv,
    const float* __restrict__ Wo, const float* __restrict__ W1,
    const float* __restrict__ W2, const float* __restrict__ bq,
    const float* __restrict__ bk, const float* __restrict__ bv,
    __hip_bfloat16* __restrict__ wt, float* __restrict__ bcat) {
  int id = blockIdx.x;
  int t = threadIdx.x;
  if (id >= 3072) {                     // bias concat: 12 blocks
    int i = (id - 3072) * 256 + t;
    bcat[i] = i < 1024 ? bq[i] : (i < 2048 ? bk[i - 1024] : bv[i - 2048]);
    return;
  }
  const float* W;
  __hip_bfloat16* Wt;
  int K, N, n0, k0;
  if (id < 1024) {                      // Wq|Wk|Wv|Wo: 256 tiles each
    int which = id >> 8, local = id & 255;
    W = which == 0 ? Wq : which == 1 ? Wk : which == 2 ? Wv : Wo;
    Wt = wt + (size_t)which * 1048576;
    K = 1024; N = 1024;
    n0 = (local & 15) * 64; k0 = (local >> 4) * 64;
  } else if (id < 2048) {               // W1: K=1024, N=4096
    int local = id - 1024;
    W = W1; Wt = wt + (size_t)4 * 1048576;
    K = 1024; N = 4096;
    n0 = (local & 63) * 64; k0 = (local >> 6) * 64;
  } else {                              // W2: K=4096, N=1024
    int local = id - 2048;
    W = W2; Wt = wt + (size_t)8 * 1048576;
    K = 4096; N = 1024;
    n0 = (local & 15) * 64; k0 = (local >> 4) * 64;
  }
  __shared__ float tl[64][68];
#pragma unroll
  for (int i = 0; i < 4; i++) {
    int kl = (t >> 4) + i * 16;
    float4 f = *(const float4*)&W[(size_t)(k0 + kl) * N + n0 + (t & 15) * 4];
    tl[kl][(t & 15) * 4 + 0] = f.x;
    tl[kl][(t & 15) * 4 + 1] = f.y;
    tl[kl][(t & 15) * 4 + 2] = f.z;
    tl[kl][(t & 15) * 4 + 3] = f.w;
  }
  __syncthreads();
  int nl = t >> 2;
#pragma unroll
  for (int i = 0; i < 4; i++) {
    int kl = (t & 3) * 4 + i * 16;
    size_t ob = (size_t)(n0 + nl) * K + k0 + kl;
    Wt[ob + 0] = __float2bfloat16(tl[kl + 0][nl]);
    Wt[ob + 1] = __float2bfloat16(tl[kl + 1][nl]);
    Wt[ob + 2] = __float2bfloat16(tl[kl + 2][nl]);
    Wt[ob + 3] = __float2bfloat16(tl[kl + 3][nl]);
  }
}

// ---------------------------------------------------------------- MFMA GEMM 128x128
// 3-buffer counted-vmcnt pipeline, 3x-unrolled with COMPILE-TIME buffer bases
// (KT-2 divisible by 3 at all call sites: 30, 126). Same sync as r18.
template <bool GELU, bool RES, bool OUTF32>
__global__ __launch_bounds__(256) void k_gemm_mfma(
    const u16* __restrict__ A, const u16* __restrict__ Bt,
    const float* __restrict__ bias, const float* __restrict__ Cin,
    void* __restrict__ Cout, int M, int K, int Nc) {
  __shared__ short As[3][128 * 32];
  __shared__ short Bs[3][128 * 32];
  int t = threadIdx.x;
  int lane = t & 63, w = t >> 6;
  int wr = w >> 1, wc = w & 1;
  int nwg = gridDim.x * gridDim.y;
  int id = blockIdx.y * gridDim.x + blockIdx.x;
  int swz = (id & 7) * (nwg >> 3) + (id >> 3);
  int bx = swz % gridDim.x, by = swz / gridDim.x;
  int row0 = by * 128, col0 = bx * 128;
  f32x4 acc[4][4];
  f32x4 z4 = {0.f, 0.f, 0.f, 0.f};
#pragma unroll
  for (int i = 0; i < 4; i++)
#pragma unroll
    for (int j = 0; j < 4; j++) acc[i][j] = z4;
  int fr = lane & 15;
  int fc = lane >> 4;
  int offA[4], offB[4];
#pragma unroll
  for (int f = 0; f < 4; f++) {
    int ra = wr * 64 + f * 16 + fr;
    offA[f] = ra * 32 + (fc ^ ((ra >> 1) & 3)) * 8;
    int rb = wc * 64 + f * 16 + fr;
    offB[f] = rb * 32 + (fc ^ ((rb >> 1) & 3)) * 8;
  }
  int c0 = t, c1 = 256 + t;
  int r0 = c0 >> 2, cl0 = (c0 & 3) ^ ((r0 >> 1) & 3);
  int r1 = c1 >> 2, cl1 = (c1 & 3) ^ ((r1 >> 1) & 3);
  const u16* pA0 = A + (size_t)(row0 + r0) * K + cl0 * 8;
  const u16* pA1 = A + (size_t)(row0 + r1) * K + cl1 * 8;
  const u16* pB0 = Bt + (size_t)(col0 + r0) * K + cl0 * 8;
  const u16* pB1 = Bt + (size_t)(col0 + r1) * K + cl1 * 8;

  auto STG = [&](short* Ab, short* Bb) {
    gload_lds16(pA0, Ab + c0 * 8);
    gload_lds16(pA1, Ab + c1 * 8);
    gload_lds16(pB0, Bb + c0 * 8);
    gload_lds16(pB1, Bb + c1 * 8);
    pA0 += 32; pA1 += 32; pB0 += 32; pB1 += 32;
  };
  auto COMPUTE = [&](const short* Ab, const short* Bb) {
    short8v af[4], bfr[4];
#pragma unroll
    for (int f = 0; f < 4; f++) {
      af[f] = *(const short8v*)(Ab + offA[f]);
      bfr[f] = *(const short8v*)(Bb + offB[f]);
    }
#pragma unroll
    for (int fi = 0; fi < 4; fi++)
#pragma unroll
      for (int fj = 0; fj < 4; fj++)
        acc[fi][fj] = __builtin_amdgcn_mfma_f32_16x16x32_bf16(
            af[fi], bfr[fj], acc[fi][fj], 0, 0, 0);
  };

  int KT = K >> 5;            // KT-2 divisible by 3 at all call sites
  STG(As[0], Bs[0]);          // k-step 0
  STG(As[1], Bs[1]);          // k-step 1
  VMCNT4(); BAR();            // step 0 resident
  for (int kt = 0; kt < KT - 2; kt += 3) {
    STG(As[2], Bs[2]); COMPUTE(As[0], Bs[0]); VMCNT4(); BAR();
    STG(As[0], Bs[0]); COMPUTE(As[1], Bs[1]); VMCNT4(); BAR();
    STG(As[1], Bs[1]); COMPUTE(As[2], Bs[2]); VMCNT4(); BAR();
  }
  COMPUTE(As[0], Bs[0]);      // k-step KT-2 ((KT-2)%3==0)
  VMCNT0(); BAR();
  COMPUTE(As[1], Bs[1]);      // k-step KT-1
#pragma unroll
  for (int fi = 0; fi < 4; fi++) {
#pragma unroll
    for (int fj = 0; fj < 4; fj++) {
#pragma unroll
      for (int ri = 0; ri < 4; ri++) {
        int row = row0 + wr * 64 + fi * 16 + (lane >> 4) * 4 + ri;
        int col = col0 + wc * 64 + fj * 16 + fr;
        float vv = acc[fi][fj][ri] + bias[col];
        if (GELU) vv = 0.5f * vv * (1.f + erf_fast(vv * 0.70710678118f));
        if (RES) vv += Cin[(size_t)row * Nc + col];
        if (OUTF32) ((float*)Cout)[(size_t)row * Nc + col] = vv;
        else ((__hip_bfloat16*)Cout)[(size_t)row * Nc + col] = __float2bfloat16(vv);
      }
    }
  }
}

// ---------------------------------------------------------------- fused key-side, MFMA, online-max, m-split
__global__ __launch_bounds__(256) void k_kv(const u16* __restrict__ kq,
    const u16* __restrict__ vq, const float* __restrict__ P,
    float* __restrict__ es, float* __restrict__ mxc, float* __restrict__ svc,
    float* __restrict__ ctx_part) {
  int bh = blockIdx.x >> 3;
  int chunk = (blockIdx.x >> 1) & 3;
  int mh = blockIdx.x & 1;
  int b = bh >> 4, hh = bh & 15;
  int t = threadIdx.x, lane = t & 63, w = t >> 6;
  int fr = lane & 15, kc = lane >> 4;
  __shared__ short Pl[128 * 64];
  __shared__ short ksl[32 * 64];
  __shared__ short vtl[64 * 32];
  __shared__ short kpl[128 * 32];
  __shared__ float dgs[32];
  __shared__ float wredk[4];
  __shared__ float svl[32][64];
#pragma unroll
  for (int i = 0; i < 4; i++) {
    int e = i * 256 + t;
    int m = e >> 3, j = e & 7;
    const float* src = P + (size_t)(mh * 128 + m) * 64 + j * 8;
    float4 f0 = *(const float4*)src;
    float4 f1 = *(const float4*)(src + 4);
    short* dst = Pl + m * 64 + ((j ^ (m & 7)) << 3);
    dst[0] = f2bs(f0.x); dst[1] = f2bs(f0.y); dst[2] = f2bs(f0.z); dst[3] = f2bs(f0.w);
    dst[4] = f2bs(f1.x); dst[5] = f2bs(f1.y); dst[6] = f2bs(f1.z); dst[7] = f2bs(f1.w);
  }
  f32x4 z4 = {0.f, 0.f, 0.f, 0.f};
  f32x4 accc[2][4];
#pragma unroll
  for (int i = 0; i < 2; i++)
#pragma unroll
    for (int j = 0; j < 4; j++) accc[i][j] = z4;
  float ksp[2] = {0.f, 0.f};
  float svp[8] = {0.f, 0.f, 0.f, 0.f, 0.f, 0.f, 0.f, 0.f};
  float m_run = -3e38f;
  int r8 = t >> 3, j8 = t & 7;
  for (int tile = 0; tile < 16; ++tile) {
    int n0 = chunk * 512 + tile * 32;
    __syncthreads();
    {
      size_t gk = ((size_t)(b * NN) + n0 + r8) * QLD + hh * 64 + j8 * 8;
      short8v k8 = *(const short8v*)(kq + gk);
      *(short8v*)(ksl + r8 * 64 + ((j8 ^ (r8 & 7)) << 3)) = k8;
      float s2 = 0.f;
#pragma unroll
      for (int ii = 0; ii < 8; ii++) { float rv = bs2f(k8[ii]); s2 += rv * rv; }
      s2 += __shfl_down(s2, 4); s2 += __shfl_down(s2, 2); s2 += __shfl_down(s2, 1);
      if (j8 == 0) dgs[r8] = 0.0625f * s2;
      short8v v8 = *(const short8v*)(vq + gk);
#pragma unroll
      for (int ii = 0; ii < 8; ii++) {
        int d = j8 * 8 + ii;
        vtl[d * 32 + (((r8 >> 3) ^ ((d >> 1) & 3)) << 3) + (r8 & 7)] = v8[ii];
        svp[ii] += bs2f(v8[ii]);
      }
    }
    __syncthreads();
    f32x4 accd[2][2];
#pragma unroll
    for (int nt = 0; nt < 2; nt++)
#pragma unroll
      for (int mt = 0; mt < 2; mt++) accd[nt][mt] = z4;
#pragma unroll
    for (int s = 0; s < 2; s++) {
      short8v afr[2];
#pragma unroll
      for (int nt = 0; nt < 2; nt++) {
        int rr = nt * 16 + fr;
        afr[nt] = *(const short8v*)(ksl + rr * 64 + (((s * 4 + kc) ^ (rr & 7)) << 3));
      }
#pragma unroll
      for (int mt = 0; mt < 2; mt++) {
        int ml = w * 32 + mt * 16 + fr;
        short8v bfp = *(const short8v*)(Pl + ml * 64 + (((s * 4 + kc) ^ (ml & 7)) << 3));
#pragma unroll
        for (int nt = 0; nt < 2; nt++)
          accd[nt][mt] = __builtin_amdgcn_mfma_f32_16x16x32_bf16(afr[nt], bfp, accd[nt][mt], 0, 0, 0);
      }
    }
    float tm = -3e38f;
#pragma unroll
    for (int nt = 0; nt < 2; nt++)
#pragma unroll
      for (int mt = 0; mt < 2; mt++) {
        accd[nt][mt] = accd[nt][mt] * DN_;
        tm = fmaxf(tm, fmaxf(fmaxf(accd[nt][mt][0], accd[nt][mt][1]),
                             fmaxf(accd[nt][mt][2], accd[nt][mt][3])));
      }
#pragma unroll
    for (int o = 32; o > 0; o >>= 1) tm = fmaxf(tm, __shfl_xor(tm, o));
    if (lane == 0) wredk[w] = tm;
    __syncthreads();
    float bm = fmaxf(fmaxf(wredk[0], wredk[1]), fmaxf(wredk[2], wredk[3]));
    float nm = fmaxf(m_run, bm);
    float fac = __expf(m_run - nm);
#pragma unroll
    for (int mt = 0; mt < 2; mt++) {
      ksp[mt] *= fac;
#pragma unroll
      for (int dt = 0; dt < 4; dt++) accc[mt][dt] = accc[mt][dt] * fac;
    }
    m_run = nm;
#pragma unroll
    for (int nt = 0; nt < 2; nt++)
#pragma unroll
      for (int mt = 0; mt < 2; mt++)
#pragma unroll
        for (int ri = 0; ri < 4; ri++) {
          int n = nt * 16 + kc * 4 + ri;
          int ml = w * 32 + mt * 16 + fr;
          float kpv = __expf(accd[nt][mt][ri] - dgs[n] - m_run);
          ksp[mt] += kpv;
          kpl[ml * 32 + (((n >> 3) ^ ((ml >> 1) & 3)) << 3) + (n & 7)] = f2bs(kpv);
        }
    short8v bvv[4];
#pragma unroll
    for (int dt = 0; dt < 4; dt++) {
      int d = dt * 16 + fr;
      bvv[dt] = *(const short8v*)(vtl + d * 32 + ((kc ^ ((d >> 1) & 3)) << 3));
    }
#pragma unroll
    for (int mt = 0; mt < 2; mt++) {
      int ml = w * 32 + mt * 16 + fr;
      short8v ak = *(const short8v*)(kpl + ml * 32 + ((kc ^ ((ml >> 1) & 3)) << 3));
#pragma unroll
      for (int dt = 0; dt < 4; dt++)
        accc[mt][dt] = __builtin_amdgcn_mfma_f32_16x16x32_bf16(ak, bvv[dt], accc[mt][dt], 0, 0, 0);
    }
  }
#pragma unroll
  for (int mt = 0; mt < 2; mt++) {
    float vv = ksp[mt];
    vv += __shfl_xor(vv, 16);
    vv += __shfl_xor(vv, 32);
    if (lane < 16)
      es[((size_t)bh * 4 + chunk) * MM + mh * 128 + w * 32 + mt * 16 + lane] = vv;
  }
  if (t == 0) mxc[((size_t)bh * 4 + chunk) * 2 + mh] = m_run;
#pragma unroll
  for (int ii = 0; ii < 8; ii++) svl[r8][j8 * 8 + ii] = svp[ii];
  __syncthreads();
  if (mh == 0 && t < 64) {
    float s = 0.f;
#pragma unroll
    for (int r = 0; r < 32; r++) s += svl[r][t];
    svc[((size_t)bh * 4 + chunk) * 64 + t] = s;
  }
  size_t base = ((size_t)(chunk * 64 + bh)) * MM * DH;
#pragma unroll
  for (int mt = 0; mt < 2; mt++)
#pragma unroll
    for (int dt = 0; dt < 4; dt++)
#pragma unroll
      for (int ri = 0; ri < 4; ri++) {
        int mg = mh * 128 + w * 32 + mt * 16 + kc * 4 + ri;
        int d = dt * 16 + fr;
        ctx_part[base + mg * 64 + d] = accc[mt][dt][ri];
      }
}

// ---------------------------------------------------------------- combine 4chunks x 2mhalves
__global__ __launch_bounds__(256) void k_ctxred(const float* __restrict__ part,
    const float* __restrict__ es, const float* __restrict__ mxc,
    const float* __restrict__ svc, float* __restrict__ ksum,
    u16* __restrict__ ctxT) {
  int bh = blockIdx.x, t = threadIdx.x;
  __shared__ float tl[64][65];
  __shared__ float facs[8];
  __shared__ float svg[64];
  float mg = -3e38f;
#pragma unroll
  for (int i = 0; i < 8; i++) mg = fmaxf(mg, mxc[(size_t)bh * 8 + i]);
  if (t < 8) facs[t] = __expf(mxc[(size_t)bh * 8 + t] - mg);
  if (t >= 64 && t < 128) {
    int d = t - 64;
    svg[d] = svc[((size_t)bh * 4 + 0) * 64 + d] + svc[((size_t)bh * 4 + 1) * 64 + d] +
             svc[((size_t)bh * 4 + 2) * 64 + d] + svc[((size_t)bh * 4 + 3) * 64 + d];
  }
  __syncthreads();
  {
    size_t eb = (size_t)bh * 4 * MM;
    int mhb = t >> 7;
    float s = es[eb + t] * facs[0 * 2 + mhb] + es[eb + MM + t] * facs[1 * 2 + mhb] +
              es[eb + 2 * MM + t] * facs[2 * 2 + mhb] + es[eb + 3 * MM + t] * facs[3 * 2 + mhb];
    ksum[bh * MM + t] = RATIO_ * (s + KEPS_ * 2048.0f);
  }
  const size_t CH = (size_t)64 * MM * DH;
  for (int mt = 0; mt < 4; mt++) {
    int mhb = mt >> 1;
    float f0 = facs[0 * 2 + mhb], f1 = facs[1 * 2 + mhb];
    float f2 = facs[2 * 2 + mhb], f3 = facs[3 * 2 + mhb];
    __syncthreads();
#pragma unroll
    for (int i = 0; i < 16; i++) {
      int e = i * 256 + t;
      int ml = e >> 6, d = e & 63;
      size_t off = (size_t)bh * MM * DH + (size_t)(mt * 64 + ml) * 64 + d;
      float ev = part[off] * f0 + part[CH + off] * f1 +
                 part[2 * CH + off] * f2 + part[3 * CH + off] * f3;
      tl[ml][d] = RATIO_ * (ev + KEPS_ * svg[d]);
    }
    __syncthreads();
#pragma unroll
    for (int i = 0; i < 16; i++) {
      int e = i * 256 + t;
      int d = e >> 6, ml = e & 63;
      ctxT[((size_t)bh * 64 + d) * 256 + mt * 64 + ml] = (u16)f2bs(tl[ml][d]);
    }
  }
}

// ---------------------------------------------------------------- fused query-side, MFMA
__global__ __launch_bounds__(256) void k_attn_fused(const u16* __restrict__ q,
    const float* __restrict__ P, const float* __restrict__ ksum,
    const u16* __restrict__ ctxT, __hip_bfloat16* __restrict__ attn) {
  int bh = blockIdx.x >> 5, rb = blockIdx.x & 31;
  int b = bh >> 4, hh = bh & 15;
  int n0 = rb * 64;
  int t = threadIdx.x, lane = t & 63, w = t >> 6;
  int fr = lane & 15, kc = lane >> 4;
  __shared__ short qsl[64 * 64];
  __shared__ short qpl[64 * 256];
  __shared__ short ctl[64 * 256];
  __shared__ float dgs[64];
  __shared__ float ks_l[MM];
  __shared__ float wred[4][64];
  __shared__ float mx_l[64];
  __shared__ float inv_l[64];
  short8v pf[4][2];
#pragma unroll
  for (int mt = 0; mt < 4; mt++)
#pragma unroll
    for (int s = 0; s < 2; s++) {
      int m = w * 64 + mt * 16 + fr;
      const float* src = P + m * 64 + s * 32 + kc * 8;
      float4 f0 = *(const float4*)src;
      float4 f1 = *(const float4*)(src + 4);
      short8v pv;
      pv[0] = f2bs(f0.x); pv[1] = f2bs(f0.y); pv[2] = f2bs(f0.z); pv[3] = f2bs(f0.w);
      pv[4] = f2bs(f1.x); pv[5] = f2bs(f1.y); pv[6] = f2bs(f1.z); pv[7] = f2bs(f1.w);
      pf[mt][s] = pv;
    }
  ks_l[t] = ksum[bh * MM + t];
  {
    int rr = t >> 2, j4 = t & 3;
    size_t gq = ((size_t)(b * NN) + n0 + rr) * QLD + hh * 64 + j4 * 16;
    short8v q0 = *(const short8v*)(q + gq);
    short8v q1 = *(const short8v*)(q + gq + 8);
    *(short8v*)(qsl + rr * 64 + (((2 * j4) ^ (rr & 7)) << 3)) = q0;
    *(short8v*)(qsl + rr * 64 + (((2 * j4 + 1) ^ (rr & 7)) << 3)) = q1;
    float s2 = 0.f;
#pragma unroll
    for (int ii = 0; ii < 8; ii++) {
      float a = bs2f(q0[ii]), c = bs2f(q1[ii]);
      s2 += a * a + c * c;
    }
    s2 += __shfl_down(s2, 2); s2 += __shfl_down(s2, 1);
    if (j4 == 0) dgs[rr] = 0.0625f * s2;
  }
#pragma unroll
  for (int i = 0; i < 8; i++) {
    int e = i * 256 + t;
    int d = e >> 5, c = e & 31;
    short8v cv = *(const short8v*)(ctxT + ((size_t)bh * 64 + d) * 256 + c * 8);
    *(short8v*)(ctl + d * 256 + ((c ^ (d & 7)) << 3)) = cv;
  }
  __syncthreads();
  f32x4 z4 = {0.f, 0.f, 0.f, 0.f};
  f32x4 accd[4][4];
#pragma unroll
  for (int i = 0; i < 4; i++)
#pragma unroll
    for (int j = 0; j < 4; j++) accd[i][j] = z4;
#pragma unroll
  for (int s = 0; s < 2; s++) {
    short8v afr[4];
#pragma unroll
    for (int nt = 0; nt < 4; nt++) {
      int rr = nt * 16 + fr;
      afr[nt] = *(const short8v*)(qsl + rr * 64 + (((s * 4 + kc) ^ (rr & 7)) << 3));
    }
#pragma unroll
    for (int mt = 0; mt < 4; mt++)
#pragma unroll
      for (int nt = 0; nt < 4; nt++)
        accd[nt][mt] = __builtin_amdgcn_mfma_f32_16x16x32_bf16(afr[nt], pf[mt][s], accd[nt][mt], 0, 0, 0);
  }
#pragma unroll
  for (int i = 0; i < 4; i++)
#pragma unroll
    for (int j = 0; j < 4; j++) accd[i][j] = accd[i][j] * DN_;
  {
    float pmx[16];
#pragma unroll
    for (int nt = 0; nt < 4; nt++)
#pragma unroll
      for (int ri = 0; ri < 4; ri++) {
        float m_ = fmaxf(fmaxf(accd[nt][0][ri], accd[nt][1][ri]),
                         fmaxf(accd[nt][2][ri], accd[nt][3][ri]));
#pragma unroll
        for (int o = 1; o < 16; o <<= 1) m_ = fmaxf(m_, __shfl_xor(m_, o));
        pmx[nt * 4 + ri] = m_;
      }
    if (fr == 0) {
#pragma unroll
      for (int nt = 0; nt < 4; nt++)
#pragma unroll
        for (int ri = 0; ri < 4; ri++)
          wred[w][nt * 16 + kc * 4 + ri] = pmx[nt * 4 + ri];
    }
  }
  __syncthreads();
  if (t < 64)
    mx_l[t] = fmaxf(fmaxf(wred[0][t], wred[1][t]), fmaxf(wred[2][t], wred[3][t]));
  __syncthreads();
  {
    float sp[16];
#pragma unroll
    for (int i = 0; i < 16; i++) sp[i] = 0.f;
#pragma unroll
    for (int nt = 0; nt < 4; nt++)
#pragma unroll
      for (int mt = 0; mt < 4; mt++)
#pragma unroll
        for (int ri = 0; ri < 4; ri++) {
          int n = nt * 16 + kc * 4 + ri;
          int m = w * 64 + mt * 16 + fr;
          float kpv = RATIO_ * (__expf(accd[nt][mt][ri] - dgs[n] - mx_l[n]) + KEPS_);
          sp[nt * 4 + ri] += kpv * ks_l[m];
          int c = m >> 3;
          qpl[n * 256 + ((c ^ (n & 7)) << 3) + (m & 7)] = f2bs(kpv);
        }
#pragma unroll
    for (int i = 0; i < 16; i++) {
#pragma unroll
      for (int o = 1; o < 16; o <<= 1) sp[i] += __shfl_xor(sp[i], o);
    }
    if (fr == 0) {
#pragma unroll
      for (int nt = 0; nt < 4; nt++)
#pragma unroll
        for (int ri = 0; ri < 4; ri++)
          wred[w][nt * 16 + kc * 4 + ri] = sp[nt * 4 + ri];
    }
  }
  __syncthreads();
  if (t < 64)
    inv_l[t] = 1.f / (wred[0][t] + wred[1][t] + wred[2][t] + wred[3][t]);
  __syncthreads();
  f32x4 acc2[4];
#pragma unroll
  for (int dt = 0; dt < 4; dt++) acc2[dt] = z4;
  int nrow = w * 16 + fr;
#pragma unroll
  for (int ks = 0; ks < 8; ks++) {
    int c = ks * 4 + kc;
    short8v aq = *(const short8v*)(qpl + nrow * 256 + ((c ^ (nrow & 7)) << 3));
#pragma unroll
    for (int dt = 0; dt < 4; dt++) {
      int d = dt * 16 + fr;
      short8v bc = *(const short8v*)(ctl + d * 256 + ((c ^ (d & 7)) << 3));
      acc2[dt] = __builtin_amdgcn_mfma_f32_16x16x32_bf16(aq, bc, acc2[dt], 0, 0, 0);
    }
  }
#pragma unroll
  for (int dt = 0; dt < 4; dt++)
#pragma unroll
    for (int ri = 0; ri < 4; ri++) {
      int n = w * 16 + kc * 4 + ri;
      int d = dt * 16 + fr;
      attn[((size_t)(b * NN) + n0 + n) * DDIM + hh * 64 + d] =
          __float2bfloat16(acc2[dt][ri] * inv_l[n]);
    }
}

// ---------------------------------------------------------------- mean over N, two-stage
__global__ __launch_bounds__(256) void k_mean1(const float* __restrict__ h,
                                               float* __restrict__ part) {
  int c = blockIdx.x >> 2, b = blockIdx.x & 3;
  int t = threadIdx.x;
  float s0 = 0.f, s1 = 0.f, s2 = 0.f, s3 = 0.f;
  for (int n = c * 32; n < c * 32 + 32; n++) {
    float4 f = *(const float4*)&h[((size_t)b * NN + n) * DDIM + t * 4];
    s0 += f.x; s1 += f.y; s2 += f.z; s3 += f.w;
  }
  float* p = part + (size_t)c * (BB * DDIM) + b * DDIM + t * 4;
  p[0] = s0; p[1] = s1; p[2] = s2; p[3] = s3;
}
__global__ __launch_bounds__(256) void k_mean2(const float* __restrict__ part,
                                               float* __restrict__ out) {
  int idx = blockIdx.x * 256 + threadIdx.x;
  float s = 0.f;
  for (int c = 0; c < 64; c++) s += part[(size_t)c * (BB * DDIM) + idx];
  out[idx] = s * (1.f / NN);
}

// ================================================================ host
extern "C" void kernel_launch(void* const* d_in, const int* in_sizes, int n_in,
                              void* d_out, int out_size, void* d_ws, size_t ws_size,
                              hipStream_t stream) {
  static const long long EXP[21] = {
      8192, 8192, 32768000, 2097152, 4096, 4096,
      4194304, 4096, 4194304, 4096, 4194304, 4096, 4194304, 4096,
      65536, 4096, 4096, 16777216, 16384, 16777216, 4096
  };
  const size_t NEED_WS = 197559552;  // bytes (<= 205.6MB proven in round 5)
  float sentinel = 0.f;
  if (n_in != 21) {
    sentinel = 100000.f + 100.f * (float)n_in;
  } else {
    for (int i = 0; i < 21; i++)
      if ((long long)in_sizes[i] != EXP[i]) { sentinel = 1000.f + 100.f * i; break; }
  }
  if (sentinel == 0.f && out_size != BB * DDIM) sentinel = 6000.f;
  if (sentinel == 0.f && ws_size < NEED_WS) {
    float units = (float)(ws_size / (32ull << 20));
    if (units > 40.f) units = 40.f;
    sentinel = 5000.f + 100.f * units;
  }
  if (sentinel != 0.f) {
    k_sentinel<<<16, 256, 0, stream>>>((float*)d_out, sentinel);
    return;
  }

  const int* x = (const int*)d_in[0];
  const float* tok  = (const float*)d_in[2];
  const float* pos  = (const float*)d_in[3];
  const float* ln1g = (const float*)d_in[4];
  const float* ln1b = (const float*)d_in[5];
  const float* wq   = (const float*)d_in[6];
  const float* bq   = (const float*)d_in[7];
  const float* wk   = (const float*)d_in[8];
  const float* bk   = (const float*)d_in[9];
  const float* wv   = (const float*)d_in[10];
  const float* bv   = (const float*)d_in[11];
  const float* wo   = (const float*)d_in[12];
  const float* bo   = (const float*)d_in[13];
  const float* proj = (const float*)d_in[14];
  const float* ln2g = (const float*)d_in[15];
  const float* ln2b = (const float*)d_in[16];
  const float* w1   = (const float*)d_in[17];
  const float* b1   = (const float*)d_in[18];
  const float* w2   = (const float*)d_in[19];
  const float* b2   = (const float*)d_in[20];

  const int BN = BB * NN;                    // 8192
  const size_t SZ = (size_t)BN * DDIM;       // 8,388,608 floats
  const size_t MEG = 1048576;
  float* ws    = (float*)d_ws;
  float* h     = ws;                          // SZ f32
  u16* qkvb    = (u16*)(ws + SZ);             // [8192][3072] bf16
  __hip_bfloat16* zb   = (__hip_bfloat16*)(ws + 4 * SZ);       // SZ bf16
  float* ctx   = ws + 4 * SZ + SZ / 2;        // ctxT bf16 region
  float* ksum  = ctx + (size_t)BB * HH * MM * DH;
  float* bmaxp = ksum + BB * HH * MM;
  float* bcat  = bmaxp + 4096;                // 3072 f32
  float* mxp   = bmaxp + BB * HH * 128;
  __hip_bfloat16* wt = (__hip_bfloat16*)(mxp + 64);            // 12M bf16
  float* ctxp  = (float*)(wt + 12 * MEG);     // 4 x 1,048,576 f32 partials
  float* esb   = ctxp + 4 * MEG;              // 64*4*256
  float* mxcb  = esb + 65536;                 // 512 (bh x chunk x mh)
  float* svcb  = mxcb + 512;                  // 64*4*64
  u16* ctxT    = (u16*)ctx;
  __hip_bfloat16* ff1b = (__hip_bfloat16*)qkvb;   // overlay (qkv dead during FFN)
  __hip_bfloat16* zab  = (__hip_bfloat16*)ctxp;   // overlay (ctxp dead after ctxred)
  float* meanp = ctxp;

  k_embed_ln<<<BN, 256, 0, stream>>>(x, tok, pos, ln1g, ln1b, h, zb);

  for (int l = 0; l < LL; l++) {
    const float* Wq = wq + (size_t)l * DDIM * DDIM;
    const float* Wk = wk + (size_t)l * DDIM * DDIM;
    const float* Wv = wv + (size_t)l * DDIM * DDIM;
    const float* Wo = wo + (size_t)l * DDIM * DDIM;
    const float* W1 = w1 + (size_t)l * DDIM * FDIM;
    const float* W2 = w2 + (size_t)l * FDIM * DDIM;
    const float* Pl = proj + (size_t)l * MM * DH;
    __hip_bfloat16* wtq = wt;             // [3072][1024] concatenated q|k|v
    __hip_bfloat16* wto = wt + 3 * MEG;
    __hip_bfloat16* wt1 = wt + 4 * MEG;
    __hip_bfloat16* wt2 = wt + 8 * MEG;

    k_wtall<<<3084, 256, 0, stream>>>(Wq, Wk, Wv, Wo, W1, W2,
                                      bq + l * DDIM, bk + l * DDIM, bv + l * DDIM,
                                      wt, bcat);

    if (l > 0)
      k_ln<<<BN, 256, 0, stream>>>(h, ln1g + l * DDIM, ln1b + l * DDIM, zb);

    dim3 gQKV(QLD / 128, BN / 128);   // (24, 64)
    k_gemm_mfma<false, false, false><<<gQKV, 256, 0, stream>>>(
        (const u16*)zb, (const u16*)wtq, bcat, nullptr, qkvb, BN, DDIM, QLD);

    k_kv<<<BB * HH * 8, 256, 0, stream>>>(qkvb + 1024, qkvb + 2048, Pl,
                                          esb, mxcb, svcb, ctxp);
    k_ctxred<<<BB * HH, 256, 0, stream>>>(ctxp, esb, mxcb, svcb, ksum, ctxT);
    k_attn_fused<<<BB * HH * 32, 256, 0, stream>>>(qkvb, Pl, ksum, ctxT, zab);

    dim3 gO(DDIM / 128, BN / 128);    // (8, 64)
    k_gemm_mfma<false, true, true><<<gO, 256, 0, stream>>>(
        (const u16*)zab, (const u16*)wto, bo + l * DDIM, h, h, BN, DDIM, DDIM);

    k_ln<<<BN, 256, 0, stream>>>(h, ln2g + l * DDIM, ln2b + l * DDIM, zb);
    dim3 g1(FDIM / 128, BN / 128);    // (32, 64)
    k_gemm_mfma<true, false, false><<<g1, 256, 0, stream>>>(
        (const u16*)zb, (const u16*)wt1, b1 + l * FDIM, nullptr, ff1b, BN, DDIM, FDIM);
    dim3 g2(DDIM / 128, BN / 128);    // (8, 64)
    k_gemm_mfma<false, true, true><<<g2, 256, 0, stream>>>(
        (const u16*)ff1b, (const u16*)wt2, b2 + l * DDIM, h, h, BN, FDIM, DDIM);
  }

  k_mean1<<<256, 256, 0, stream>>>(h, meanp);
  k_mean2<<<16, 256, 0, stream>>>(meanp, (float*)d_out);
}